// Round 4
// baseline (1388.355 us; speedup 1.0000x reference)
//
#include <hip/hip_runtime.h>
#include <math.h>

// LLaMA-style decoder forward: B=2 S=512 D=1024 H=16 F=4096 V=32000 L=2 R=16
constexpr int B = 2, S = 512, D = 1024, H = 16, F = 4096, V = 32000, L = 2, R = 16, DH = 64;
constexpr int BS = B * S;          // 1024 rows
constexpr float LORA_SCALE = 2.0f; // alpha/r
constexpr float EPS = 1e-5f;
constexpr int RS_QKV = 3 * D;      // fused qkv row stride
constexpr int RS_GU  = 2 * F;      // fused g|u row stride

typedef __attribute__((ext_vector_type(8))) __bf16 bf16x8;
typedef __attribute__((ext_vector_type(4))) float f32x4;

__device__ __forceinline__ unsigned short f2bf(float f) {
  unsigned u = __builtin_bit_cast(unsigned, f);
  unsigned r = (u + 0x7FFFu + ((u >> 16) & 1u)) >> 16;  // RNE
  return (unsigned short)r;
}
__device__ __forceinline__ float bf2f(unsigned short us) {
  return __builtin_bit_cast(float, (unsigned)us << 16);
}
__device__ __forceinline__ void load_lds16(const void* g, void* l) {
  __builtin_amdgcn_global_load_lds((const __attribute__((address_space(1))) void*)g,
                                   (__attribute__((address_space(3))) void*)l, 16, 0, 0);
}

struct Ptr3 { const float* p[3]; };

// ---------------- RoPE cache ----------------
__global__ void rope_cache_kernel(float* __restrict__ cosb, float* __restrict__ sinb) {
  int s = blockIdx.x, j = threadIdx.x;  // j in [0,32)
  float inv = __expf(-(float)j * (9.210340371976184f / 32.0f));
  float ang = (float)s * inv;
  float c = cosf(ang), sn = sinf(ang);
  cosb[s * DH + j] = c;  cosb[s * DH + j + 32] = c;
  sinb[s * DH + j] = sn; sinb[s * DH + j + 32] = sn;
}

// ---------------- Embedding gather ----------------
__global__ void embed_kernel(const int* __restrict__ ids, const float* __restrict__ emb,
                             float* __restrict__ h) {
  int row = blockIdx.x, t = threadIdx.x;
  int id = ids[row];
  ((float4*)(h + (size_t)row * D))[t] = ((const float4*)(emb + (size_t)id * D))[t];
}

// ---------------- RMSNorm -> bf16 ----------------
__global__ void rmsnorm_bf16_kernel(const float* __restrict__ x, const float* __restrict__ w,
                                    unsigned short* __restrict__ y) {
  int row = blockIdx.x, t = threadIdx.x;
  float4 xv = ((const float4*)(x + (size_t)row * D))[t];
  float ss = xv.x * xv.x + xv.y * xv.y + xv.z * xv.z + xv.w * xv.w;
  __shared__ float red[256];
  red[t] = ss; __syncthreads();
  for (int s2 = 128; s2; s2 >>= 1) { if (t < s2) red[t] += red[t + s2]; __syncthreads(); }
  float rinv = rsqrtf(red[0] * (1.0f / D) + EPS);
  float4 wv = ((const float4*)w)[t];
  ushort4 o;
  o.x = f2bf(xv.x * rinv * wv.x); o.y = f2bf(xv.y * rinv * wv.y);
  o.z = f2bf(xv.z * rinv * wv.z); o.w = f2bf(xv.w * rinv * wv.w);
  ((ushort4*)(y + (size_t)row * D))[t] = o;
}

// ---------------- f32 [K,N] -> bf16 [N,K] transpose (64x64, vectorized) ----------------
__global__ __launch_bounds__(256) void transpose_bf16_kernel(const float* __restrict__ src,
                                      unsigned short* __restrict__ dst, int K, int N) {
  __shared__ unsigned short tile[64 * 68];  // stride 68: 4-way instead of 8-way write conflicts
  int n0 = blockIdx.x * 64, k0 = blockIdx.y * 64;
  int t = threadIdx.x;
  int rr = t >> 4, c4 = (t & 15) << 2;
#pragma unroll
  for (int i = 0; i < 4; ++i) {
    int row = i * 16 + rr;
    float4 v = *(const float4*)(src + (size_t)(k0 + row) * N + n0 + c4);
    tile[(c4 + 0) * 68 + row] = f2bf(v.x);
    tile[(c4 + 1) * 68 + row] = f2bf(v.y);
    tile[(c4 + 2) * 68 + row] = f2bf(v.z);
    tile[(c4 + 3) * 68 + row] = f2bf(v.w);
  }
  __syncthreads();
#pragma unroll
  for (int i = 0; i < 4; ++i) {
    int row = i * 16 + rr;
    *(ushort4*)(dst + (size_t)(n0 + row) * K + k0 + c4) = *(const ushort4*)(tile + row * 68 + c4);
  }
}

// ---------------- bf16 MFMA GEMM + fused LoRA epilogue ----------------
// C = [C +] A @ Bt^T [+ 2 * t2 @ b].  A:[M,K] bf16, Bt:[N,K] bf16, C:[M,N] f32.
// t2:[M, NA*16] f32, bp.p[sel]:[16, W] f32 with W = 1<<logW, sel = n0>>logW.
// Block swizzle: XCD-chunked (m204 bijective) + M-inner decode -> each XCD owns a
// contiguous N-range so B-panels are L2-fetched once chip-wide.
template <int BN, bool ACC, int NA>
__global__ __launch_bounds__(256) void gemm_bf16_kernel(
    const unsigned short* __restrict__ A, const unsigned short* __restrict__ Bt,
    float* __restrict__ C, int M, int N, int K,
    const float* __restrict__ t2, Ptr3 bp, int logW) {
  constexpr int WM = (BN == 128) ? 2 : 4;   // wave grid rows
  constexpr int RW = 128 / WM;              // rows per wave
  constexpr int MI = RW / 16;
  constexpr int BCH = BN / 32;
  __shared__ __align__(16) unsigned short As[128 * 64];
  __shared__ __align__(16) unsigned short Bs[BN * 64];
  int t = threadIdx.x;
  int lane = t & 63, wave = t >> 6;
  int wr = (BN == 128) ? (wave >> 1) : wave;
  int wc = (BN == 128) ? (wave & 1) : 0;
  // ---- XCD-chunked, M-inner block swizzle ----
  int MT = gridDim.y, NT = gridDim.x;
  int nwg = MT * NT;
  int orig = blockIdx.y * NT + blockIdx.x;
  int qq = nwg >> 3, rr8 = nwg & 7;
  int xcd = orig & 7, pos = orig >> 3;
  int wg = (xcd < rr8) ? (xcd * (qq + 1) + pos) : (rr8 * (qq + 1) + (xcd - rr8) * qq + pos);
  int m0 = (wg % MT) * 128, n0 = (wg / MT) * BN;
  int fr = lane & 15, fq = lane >> 4;
  f32x4 acc[MI][4] = {};
  for (int k0 = 0; k0 < K; k0 += 64) {
#pragma unroll
    for (int c = 0; c < 4; ++c) {
      int i = c * 256 + t;
      int row = i >> 3, cc = i & 7;
      load_lds16(A + (size_t)(m0 + row) * K + k0 + cc * 8, &As[i * 8]);
    }
#pragma unroll
    for (int c = 0; c < BCH; ++c) {
      int i = c * 256 + t;
      int row = i >> 3, cc = i & 7;
      load_lds16(Bt + (size_t)(n0 + row) * K + k0 + cc * 8, &Bs[i * 8]);
    }
    __syncthreads();
#pragma unroll
    for (int kk = 0; kk < 2; ++kk) {
      bf16x8 af[MI], bfr[4];
#pragma unroll
      for (int mi = 0; mi < MI; ++mi)
        af[mi] = *(const bf16x8*)(As + (wr * RW + mi * 16 + fr) * 64 + kk * 32 + fq * 8);
#pragma unroll
      for (int ni = 0; ni < 4; ++ni)
        bfr[ni] = *(const bf16x8*)(Bs + (wc * 64 + ni * 16 + fr) * 64 + kk * 32 + fq * 8);
#pragma unroll
      for (int mi = 0; mi < MI; ++mi)
#pragma unroll
        for (int ni = 0; ni < 4; ++ni)
          acc[mi][ni] = __builtin_amdgcn_mfma_f32_16x16x32_bf16(af[mi], bfr[ni], acc[mi][ni], 0, 0, 0);
    }
    __syncthreads();
  }
  // ---- epilogue (C/D layout: col=lane&15, row=(lane>>4)*4+j) + fused LoRA ----
  int W = 1 << logW;
  const float* bsel = nullptr;
  int sel = 0;
  if (NA > 0) { sel = n0 >> logW; bsel = bp.p[sel]; }
#pragma unroll
  for (int mi = 0; mi < MI; ++mi) {
#pragma unroll
    for (int j = 0; j < 4; ++j) {
      int r = m0 + wr * RW + mi * 16 + fq * 4 + j;
      float trg[16];
      if (NA > 0) {
        const float* tr = t2 + (size_t)r * (NA * 16) + sel * 16;
#pragma unroll
        for (int k = 0; k < 16; ++k) trg[k] = tr[k];
      }
#pragma unroll
      for (int ni = 0; ni < 4; ++ni) {
        int cl = n0 + wc * 64 + ni * 16 + fr;
        float v = acc[mi][ni][j];
        if (NA > 0) {
          int nn = cl & (W - 1);
          float s = 0.0f;
#pragma unroll
          for (int k = 0; k < 16; ++k) s = fmaf(trg[k], bsel[k * W + nn], s);
          v += LORA_SCALE * s;
        }
        size_t idx = (size_t)r * N + cl;
        C[idx] = ACC ? C[idx] + v : v;
      }
    }
  }
}

// ---------------- LoRA: t2[M, NA*16] = x_bf16[M,K] @ [a0|a1|a2] ----------------
template <int NA>
__global__ void lora_xa_kernel(const unsigned short* __restrict__ xb, Ptr3 ap,
                               float* __restrict__ t2, int K) {
  int row = blockIdx.x, t = threadIdx.x;  // 256 threads
  __shared__ float xs[4096];
  __shared__ float red[256];
  for (int k = t; k < K; k += 256) xs[k] = bf2f(xb[(size_t)row * K + k]);
  __syncthreads();
  int n = t & 15, g = t >> 4;
#pragma unroll
  for (int ad = 0; ad < NA; ++ad) {
    const float* a = ap.p[ad];
    float s = 0.0f;
    for (int k = g; k < K; k += 16) s = fmaf(xs[k], a[k * 16 + n], s);
    red[t] = s; __syncthreads();
    for (int h2 = 128; h2 >= 16; h2 >>= 1) { if (t < h2) red[t] += red[t + h2]; __syncthreads(); }
    if (t < 16) t2[row * (NA * 16) + ad * 16 + t] = red[t];
    __syncthreads();
  }
}

// ---------------- RoPE apply in-place on fused qkv (q and k halves in one dispatch) ----------------
__global__ void rope_apply_qk_kernel(float* __restrict__ qkv, const float* __restrict__ cosb,
                                     const float* __restrict__ sinb) {
  int i = blockIdx.x * 256 + threadIdx.x;
  constexpr int total = B * S * H * 32;
  int which = (i >= total) ? 1 : 0;   // 0 = q, 1 = k
  int ii = i - which * total;
  int dh = ii & 31;
  int rest = ii >> 5;
  int hh = rest % H;
  int bs = rest / H;
  int s = bs % S;
  size_t base = (size_t)bs * RS_QKV + which * D + hh * DH;
  float x1 = qkv[base + dh], x2 = qkv[base + dh + 32];
  float c = cosb[s * DH + dh], sn = sinb[s * DH + dh];
  qkv[base + dh]      = x1 * c - x2 * sn;
  qkv[base + dh + 32] = x2 * c + x1 * sn;
}

// ---------------- Flash attention, bf16 MFMA ----------------
// Block: 256 thr = 4 waves; one block per (b, h, q-tile of 64). Wave w: q rows [w*16, w*16+16).
__global__ __launch_bounds__(256) void attn_mfma_kernel(
    const float* __restrict__ qkv, const int* __restrict__ amask,
    unsigned short* __restrict__ o) {
  __shared__ unsigned short Qs[64 * 72];
  __shared__ unsigned short Ks[64 * 72];
  __shared__ unsigned short Vt[64 * 72];   // [dh][key]
  __shared__ unsigned short Ps[4][16 * 72];
  __shared__ float msk[64];
  int bid = blockIdx.x;
  int qt = bid & 7, hh = (bid >> 3) & (H - 1), b = bid >> 7;
  int t = threadIdx.x;
  int lane = t & 63, w = t >> 6;
  int fr = lane & 15, fq = lane >> 4;
  int rr = t >> 4, c4 = (t & 15) << 2;
  size_t rowbase = (size_t)b * S;
  int q0 = qt * 64;
  const float scale = 0.125f;  // 1/sqrt(64)
#pragma unroll
  for (int i = 0; i < 4; ++i) {
    int row = i * 16 + rr;
    float4 v = *(const float4*)(qkv + (rowbase + q0 + row) * RS_QKV + hh * DH + c4);
    Qs[row * 72 + c4 + 0] = f2bf(v.x); Qs[row * 72 + c4 + 1] = f2bf(v.y);
    Qs[row * 72 + c4 + 2] = f2bf(v.z); Qs[row * 72 + c4 + 3] = f2bf(v.w);
  }
  f32x4 oacc[4] = {};
  float m_old[4] = {-1e30f, -1e30f, -1e30f, -1e30f};
  float l[4] = {};
  int qbase = q0 + w * 16;
  for (int kt = 0; kt <= qt; ++kt) {
    int kk0 = kt * 64;
#pragma unroll
    for (int i = 0; i < 4; ++i) {
      int row = i * 16 + rr;
      float4 kv = *(const float4*)(qkv + (rowbase + kk0 + row) * RS_QKV + D + hh * DH + c4);
      Ks[row * 72 + c4 + 0] = f2bf(kv.x); Ks[row * 72 + c4 + 1] = f2bf(kv.y);
      Ks[row * 72 + c4 + 2] = f2bf(kv.z); Ks[row * 72 + c4 + 3] = f2bf(kv.w);
      float4 vv = *(const float4*)(qkv + (rowbase + kk0 + row) * RS_QKV + 2 * D + hh * DH + c4);
      Vt[(c4 + 0) * 72 + row] = f2bf(vv.x); Vt[(c4 + 1) * 72 + row] = f2bf(vv.y);
      Vt[(c4 + 2) * 72 + row] = f2bf(vv.z); Vt[(c4 + 3) * 72 + row] = f2bf(vv.w);
    }
    if (t < 64) msk[t] = (amask[b * S + kk0 + t] > 0) ? 0.0f : -1e9f;
    __syncthreads();
    bf16x8 aq[2];
    aq[0] = *(const bf16x8*)(Qs + (w * 16 + fr) * 72 + fq * 8);
    aq[1] = *(const bf16x8*)(Qs + (w * 16 + fr) * 72 + 32 + fq * 8);
    f32x4 sacc[4];
#pragma unroll
    for (int ct = 0; ct < 4; ++ct) {
      bf16x8 bk0 = *(const bf16x8*)(Ks + (ct * 16 + fr) * 72 + fq * 8);
      bf16x8 bk1 = *(const bf16x8*)(Ks + (ct * 16 + fr) * 72 + 32 + fq * 8);
      f32x4 z = {};
      z = __builtin_amdgcn_mfma_f32_16x16x32_bf16(aq[0], bk0, z, 0, 0, 0);
      sacc[ct] = __builtin_amdgcn_mfma_f32_16x16x32_bf16(aq[1], bk1, z, 0, 0, 0);
    }
    float sv[4][4];
#pragma unroll
    for (int ct = 0; ct < 4; ++ct) {
      int kg = kk0 + ct * 16 + fr;
      float mk = msk[ct * 16 + fr];
#pragma unroll
      for (int j = 0; j < 4; ++j) {
        int qg = qbase + fq * 4 + j;
        float s = sacc[ct][j] * scale + mk;
        sv[ct][j] = (kg > qg) ? -1e9f : s;
      }
    }
    float mnew[4], f[4], rsum[4];
#pragma unroll
    for (int j = 0; j < 4; ++j) {
      float mt = fmaxf(fmaxf(sv[0][j], sv[1][j]), fmaxf(sv[2][j], sv[3][j]));
      for (int off = 1; off < 16; off <<= 1) mt = fmaxf(mt, __shfl_xor(mt, off));
      mnew[j] = fmaxf(m_old[j], mt);
      f[j] = __expf(m_old[j] - mnew[j]);
      float rs = 0.0f;
#pragma unroll
      for (int ct = 0; ct < 4; ++ct) {
        float e = __expf(sv[ct][j] - mnew[j]);
        sv[ct][j] = e;
        rs += e;
      }
      for (int off = 1; off < 16; off <<= 1) rs += __shfl_xor(rs, off);
      rsum[j] = rs;
      l[j] = l[j] * f[j] + rsum[j];
      m_old[j] = mnew[j];
#pragma unroll
      for (int dt = 0; dt < 4; ++dt) oacc[dt][j] *= f[j];
    }
#pragma unroll
    for (int ct = 0; ct < 4; ++ct)
#pragma unroll
      for (int j = 0; j < 4; ++j)
        Ps[w][(fq * 4 + j) * 72 + ct * 16 + fr] = f2bf(sv[ct][j]);
    __syncthreads();
    bf16x8 pa[2];
    pa[0] = *(const bf16x8*)(&Ps[w][fr * 72 + fq * 8]);
    pa[1] = *(const bf16x8*)(&Ps[w][fr * 72 + 32 + fq * 8]);
#pragma unroll
    for (int dt = 0; dt < 4; ++dt) {
      bf16x8 vb0 = *(const bf16x8*)(Vt + (dt * 16 + fr) * 72 + fq * 8);
      bf16x8 vb1 = *(const bf16x8*)(Vt + (dt * 16 + fr) * 72 + 32 + fq * 8);
      oacc[dt] = __builtin_amdgcn_mfma_f32_16x16x32_bf16(pa[0], vb0, oacc[dt], 0, 0, 0);
      oacc[dt] = __builtin_amdgcn_mfma_f32_16x16x32_bf16(pa[1], vb1, oacc[dt], 0, 0, 0);
    }
    __syncthreads();
  }
#pragma unroll
  for (int j = 0; j < 4; ++j) {
    float rinv = 1.0f / l[j];
    int qrow = qbase + fq * 4 + j;
#pragma unroll
    for (int dt = 0; dt < 4; ++dt)
      o[(rowbase + qrow) * D + hh * DH + dt * 16 + fr] = f2bf(oacc[dt][j] * rinv);
  }
}

// ---------------- SwiGLU on fused [BS][2F]: gbf = bf16(silu(g)*u) ----------------
__global__ void silu_mul_kernel(const float* __restrict__ gu, unsigned short* __restrict__ gbf) {
  int i = blockIdx.x * 256 + threadIdx.x;  // over BS*F
  int row = i >> 12, j = i & (F - 1);
  float gv = gu[(size_t)row * RS_GU + j];
  float uv = gu[(size_t)row * RS_GU + F + j];
  float sg = 1.0f / (1.0f + __expf(-gv));
  gbf[i] = f2bf(gv * sg * uv);
}

// ---------------- Value head ----------------
__global__ void value_kernel(const unsigned short* __restrict__ hf, const float* __restrict__ vw,
                             const float* __restrict__ vb, float* __restrict__ out) {
  int row = blockIdx.x, t = threadIdx.x;
  float acc = 0.0f;
  for (int d = t; d < D; d += 256) acc = fmaf(bf2f(hf[(size_t)row * D + d]), vw[d], acc);
  __shared__ float red[256];
  red[t] = acc; __syncthreads();
  for (int s2 = 128; s2; s2 >>= 1) { if (t < s2) red[t] += red[t + s2]; __syncthreads(); }
  if (t == 0) out[row] = red[0] + vb[0];
}

extern "C" void kernel_launch(void* const* d_in, const int* in_sizes, int n_in,
                              void* d_out, int out_size, void* d_ws, size_t ws_size,
                              hipStream_t stream) {
  const int*   ids     = (const int*)d_in[0];
  const int*   amask   = (const int*)d_in[1];
  const float* emb     = (const float*)d_in[2];
  const float* ln1     = (const float*)d_in[3];
  const float* ln2     = (const float*)d_in[4];
  const float* wq = (const float*)d_in[5],  *aq = (const float*)d_in[6],  *bq = (const float*)d_in[7];
  const float* wk = (const float*)d_in[8],  *ak = (const float*)d_in[9],  *bk = (const float*)d_in[10];
  const float* wv = (const float*)d_in[11], *av = (const float*)d_in[12], *bv = (const float*)d_in[13];
  const float* wo = (const float*)d_in[14], *ao = (const float*)d_in[15], *bo = (const float*)d_in[16];
  const float* wg = (const float*)d_in[17], *ag = (const float*)d_in[18], *bg = (const float*)d_in[19];
  const float* wu = (const float*)d_in[20], *au = (const float*)d_in[21], *bu = (const float*)d_in[22];
  const float* wd = (const float*)d_in[23], *ad = (const float*)d_in[24], *bd = (const float*)d_in[25];
  const float* final_ln  = (const float*)d_in[26];
  const float* lm_head_w = (const float*)d_in[27];
  const float* value_w   = (const float*)d_in[28];
  const float* value_b   = (const float*)d_in[29];

  float* out    = (float*)d_out;
  float* logits = out;
  float* values = out + (size_t)BS * V;

  // ---- workspace ----
  float* Wf = (float*)d_ws;
  float* cosb = Wf; Wf += S * DH;
  float* sinb = Wf; Wf += S * DH;
  float* h    = Wf; Wf += (size_t)BS * D;
  float* qkv  = Wf; Wf += (size_t)BS * RS_QKV;
  float* gu   = Wf; Wf += (size_t)BS * RS_GU;
  float* t2   = Wf; Wf += (size_t)BS * 48;
  unsigned short* Wb = (unsigned short*)Wf;
  unsigned short* x_bf  = Wb; Wb += (size_t)BS * D;
  unsigned short* wqkvT = Wb; Wb += (size_t)L * 3 * D * D;
  unsigned short* woT   = Wb; Wb += (size_t)L * D * D;
  unsigned short* wguT  = Wb; Wb += (size_t)L * 2 * D * F;
  unsigned short* wdT   = Wb; Wb += (size_t)L * F * D;
  unsigned short* lmT   = Wb; Wb += (size_t)D * V;
  // aliases into dead regions (obf dead before gu written; gbf dead before next qkv)
  unsigned short* obf = (unsigned short*)gu;   // [BS][D] bf16 inside gu
  unsigned short* gbf = (unsigned short*)qkv;  // [BS][F] bf16 inside qkv

  auto T = [&](const float* src, unsigned short* dst, int K_, int N_) {
    transpose_bf16_kernel<<<dim3(N_ / 64, K_ / 64), 256, 0, stream>>>(src, dst, K_, N_);
  };
  for (int l = 0; l < L; ++l) {
    size_t DD = (size_t)D * D, DF = (size_t)D * F;
    T(wq + l * DD, wqkvT + (size_t)l * 3 * DD, D, D);
    T(wk + l * DD, wqkvT + (size_t)l * 3 * DD + DD, D, D);
    T(wv + l * DD, wqkvT + (size_t)l * 3 * DD + 2 * DD, D, D);
    T(wo + l * DD, woT + l * DD, D, D);
    T(wg + l * DF, wguT + (size_t)l * 2 * DF, D, F);
    T(wu + l * DF, wguT + (size_t)l * 2 * DF + DF, D, F);
    T(wd + l * DF, wdT + l * DF, F, D);
  }
  T(lm_head_w, lmT, D, V);

  rope_cache_kernel<<<dim3(S), dim3(32), 0, stream>>>(cosb, sinb);
  embed_kernel<<<dim3(BS), dim3(256), 0, stream>>>(ids, emb, h);

  constexpr int ROPE_BLOCKS = (B * S * H * 32 + 255) / 256;
  Ptr3 nop = {{nullptr, nullptr, nullptr}};

  for (int l = 0; l < L; ++l) {
    size_t DD = (size_t)D * D, DF = (size_t)D * F;
    size_t oDR = (size_t)l * D * R, oRD = (size_t)l * R * D;
    size_t oRF = (size_t)l * R * F, oFR = (size_t)l * F * R;

    // ---- attention block ----
    rmsnorm_bf16_kernel<<<dim3(BS), 256, 0, stream>>>(h, ln1 + (size_t)l * D, x_bf);
    { Ptr3 ap = {{aq + oDR, ak + oDR, av + oDR}};
      lora_xa_kernel<3><<<dim3(BS), 256, 0, stream>>>(x_bf, ap, t2, D);
      Ptr3 bp = {{bq + oRD, bk + oRD, bv + oRD}};
      gemm_bf16_kernel<128, false, 3><<<dim3(3 * D / 128, BS / 128), 256, 0, stream>>>(
          x_bf, wqkvT + (size_t)l * 3 * DD, qkv, BS, 3 * D, D, t2, bp, 10); }
    rope_apply_qk_kernel<<<dim3(2 * ROPE_BLOCKS), 256, 0, stream>>>(qkv, cosb, sinb);

    attn_mfma_kernel<<<dim3(B * H * (S / 64)), 256, 0, stream>>>(qkv, amask, obf);

    { Ptr3 ap = {{ao + oDR, nullptr, nullptr}};
      lora_xa_kernel<1><<<dim3(BS), 256, 0, stream>>>(obf, ap, t2, D);
      Ptr3 bp = {{bo + oRD, nullptr, nullptr}};
      gemm_bf16_kernel<64, true, 1><<<dim3(D / 64, BS / 128), 256, 0, stream>>>(
          obf, woT + l * DD, h, BS, D, D, t2, bp, 10); }

    // ---- MLP block ----
    rmsnorm_bf16_kernel<<<dim3(BS), 256, 0, stream>>>(h, ln2 + (size_t)l * D, x_bf);
    { Ptr3 ap = {{ag + oDR, au + oDR, nullptr}};
      lora_xa_kernel<2><<<dim3(BS), 256, 0, stream>>>(x_bf, ap, t2, D);
      Ptr3 bp = {{bg + oRF, bu + oRF, nullptr}};
      gemm_bf16_kernel<128, false, 2><<<dim3(2 * F / 128, BS / 128), 256, 0, stream>>>(
          x_bf, wguT + (size_t)l * 2 * DF, gu, BS, 2 * F, D, t2, bp, 12); }

    silu_mul_kernel<<<dim3(BS * F / 256), 256, 0, stream>>>(gu, gbf);

    { Ptr3 ap = {{ad + oFR, nullptr, nullptr}};
      lora_xa_kernel<1><<<dim3(BS), 256, 0, stream>>>(gbf, ap, t2, F);
      Ptr3 bp = {{bd + oRD, nullptr, nullptr}};
      gemm_bf16_kernel<64, true, 1><<<dim3(D / 64, BS / 128), 256, 0, stream>>>(
          gbf, wdT + l * DF, h, BS, D, F, t2, bp, 10); }
  }

  // ---- final norm + heads ----
  rmsnorm_bf16_kernel<<<dim3(BS), 256, 0, stream>>>(h, final_ln, x_bf);
  gemm_bf16_kernel<128, false, 0><<<dim3(V / 128, BS / 128), 256, 0, stream>>>(
      x_bf, lmT, logits, BS, V, D, nullptr, nop, 10);
  value_kernel<<<dim3(BS), 256, 0, stream>>>(x_bf, value_w, value_b, values);
}

// Round 5
// 1163.434 us; speedup vs baseline: 1.1933x; 1.1933x over previous
//
#include <hip/hip_runtime.h>
#include <math.h>

// LLaMA-style decoder forward: B=2 S=512 D=1024 H=16 F=4096 V=32000 L=2 R=16
constexpr int B = 2, S = 512, D = 1024, H = 16, F = 4096, V = 32000, L = 2, R = 16, DH = 64;
constexpr int BS = B * S;          // 1024 rows
constexpr float LORA_SCALE = 2.0f; // alpha/r
constexpr float EPS = 1e-5f;
constexpr int RS_QKV = 3 * D;      // fused qkv row stride
constexpr int RS_GU  = 2 * F;      // fused g|u row stride

typedef __attribute__((ext_vector_type(8))) __bf16 bf16x8;
typedef __attribute__((ext_vector_type(4))) float f32x4;

__device__ __forceinline__ unsigned short f2bf(float f) {
  unsigned u = __builtin_bit_cast(unsigned, f);
  unsigned r = (u + 0x7FFFu + ((u >> 16) & 1u)) >> 16;  // RNE
  return (unsigned short)r;
}
__device__ __forceinline__ float bf2f(unsigned short us) {
  return __builtin_bit_cast(float, (unsigned)us << 16);
}
__device__ __forceinline__ void load_lds16(const void* g, void* l) {
  __builtin_amdgcn_global_load_lds((const __attribute__((address_space(1))) void*)g,
                                   (__attribute__((address_space(3))) void*)l, 16, 0, 0);
}

struct Ptr3 { const float* p[3]; };

// ---------------- RoPE cache ----------------
__global__ void rope_cache_kernel(float* __restrict__ cosb, float* __restrict__ sinb) {
  int s = blockIdx.x, j = threadIdx.x;  // j in [0,32)
  float inv = __expf(-(float)j * (9.210340371976184f / 32.0f));
  float ang = (float)s * inv;
  float c = cosf(ang), sn = sinf(ang);
  cosb[s * DH + j] = c;  cosb[s * DH + j + 32] = c;
  sinb[s * DH + j] = sn; sinb[s * DH + j + 32] = sn;
}

// ---------------- Embedding gather ----------------
__global__ void embed_kernel(const int* __restrict__ ids, const float* __restrict__ emb,
                             float* __restrict__ h) {
  int row = blockIdx.x, t = threadIdx.x;
  int id = ids[row];
  ((float4*)(h + (size_t)row * D))[t] = ((const float4*)(emb + (size_t)id * D))[t];
}

// ---------------- RMSNorm -> bf16 (final norm, no LoRA) ----------------
__global__ void rmsnorm_bf16_kernel(const float* __restrict__ x, const float* __restrict__ w,
                                    unsigned short* __restrict__ y) {
  int row = blockIdx.x, t = threadIdx.x;
  float4 xv = ((const float4*)(x + (size_t)row * D))[t];
  float ss = xv.x * xv.x + xv.y * xv.y + xv.z * xv.z + xv.w * xv.w;
  __shared__ float red[256];
  red[t] = ss; __syncthreads();
  for (int s2 = 128; s2; s2 >>= 1) { if (t < s2) red[t] += red[t + s2]; __syncthreads(); }
  float rinv = rsqrtf(red[0] * (1.0f / D) + EPS);
  float4 wv = ((const float4*)w)[t];
  ushort4 o;
  o.x = f2bf(xv.x * rinv * wv.x); o.y = f2bf(xv.y * rinv * wv.y);
  o.z = f2bf(xv.z * rinv * wv.z); o.w = f2bf(xv.w * rinv * wv.w);
  ((ushort4*)(y + (size_t)row * D))[t] = o;
}

// ---------------- Fused RMSNorm + LoRA down-proj: x_bf + t2e[row][64] ----------------
// t2e cols [ad*16, ad*16+16) = bf16(2 * (xnorm @ a_ad)); cols [NA*16,64) zeroed.
template <int NA>
__global__ void rms_lora_kernel(const float* __restrict__ hp, const float* __restrict__ w,
                                Ptr3 ap, unsigned short* __restrict__ xbf,
                                unsigned short* __restrict__ t2e) {
  int row = blockIdx.x, t = threadIdx.x;  // 256 threads
  __shared__ float xs[D];
  __shared__ float red[256];
  float4 xv = ((const float4*)(hp + (size_t)row * D))[t];
  float ss = xv.x * xv.x + xv.y * xv.y + xv.z * xv.z + xv.w * xv.w;
  red[t] = ss; __syncthreads();
  for (int s2 = 128; s2; s2 >>= 1) { if (t < s2) red[t] += red[t + s2]; __syncthreads(); }
  float rinv = rsqrtf(red[0] * (1.0f / D) + EPS);
  float4 wv = ((const float4*)w)[t];
  float4 nx;
  nx.x = xv.x * rinv * wv.x; nx.y = xv.y * rinv * wv.y;
  nx.z = xv.z * rinv * wv.z; nx.w = xv.w * rinv * wv.w;
  xs[t * 4 + 0] = nx.x; xs[t * 4 + 1] = nx.y; xs[t * 4 + 2] = nx.z; xs[t * 4 + 3] = nx.w;
  ushort4 o;
  o.x = f2bf(nx.x); o.y = f2bf(nx.y); o.z = f2bf(nx.z); o.w = f2bf(nx.w);
  ((ushort4*)(xbf + (size_t)row * D))[t] = o;
  if (t >= NA * 16 && t < 64) t2e[(size_t)row * 64 + t] = 0;
  __syncthreads();
  int n = t & 15, g = t >> 4;
#pragma unroll
  for (int ad = 0; ad < NA; ++ad) {
    const float* a = ap.p[ad];
    float s = 0.0f;
    for (int k = g; k < D; k += 16) s = fmaf(xs[k], a[k * 16 + n], s);
    red[t] = s; __syncthreads();
    for (int h2 = 128; h2 >= 16; h2 >>= 1) { if (t < h2) red[t] += red[t + h2]; __syncthreads(); }
    if (t < 16) t2e[(size_t)row * 64 + ad * 16 + t] = f2bf(LORA_SCALE * red[t]);
    __syncthreads();
  }
}

// ---------------- LoRA down-proj from bf16 activation (o-proj): t2e[row][64] ----------------
__global__ void lora_o_kernel(const unsigned short* __restrict__ xb, const float* __restrict__ a,
                              unsigned short* __restrict__ t2e) {
  int row = blockIdx.x, t = threadIdx.x;  // 256 threads, K=D
  __shared__ float xs[D];
  __shared__ float red[256];
  for (int k = t; k < D; k += 256) xs[k] = bf2f(xb[(size_t)row * D + k]);
  if (t >= 16 && t < 64) t2e[(size_t)row * 64 + t] = 0;
  __syncthreads();
  int n = t & 15, g = t >> 4;
  float s = 0.0f;
  for (int k = g; k < D; k += 16) s = fmaf(xs[k], a[k * 16 + n], s);
  red[t] = s; __syncthreads();
  for (int h2 = 128; h2 >= 16; h2 >>= 1) { if (t < h2) red[t] += red[t + h2]; __syncthreads(); }
  if (t < 16) t2e[(size_t)row * 64 + t] = f2bf(LORA_SCALE * red[t]);
}

// ---------------- Fused SwiGLU + LoRA down-proj: gbf + t2e ----------------
__global__ void silu_lora_kernel(const float* __restrict__ gu, const float* __restrict__ a,
                                 unsigned short* __restrict__ gbf, unsigned short* __restrict__ t2e) {
  int row = blockIdx.x, t = threadIdx.x;  // 256 threads
  __shared__ float xs[F];   // 16KB
  __shared__ float red[256];
#pragma unroll
  for (int i = 0; i < 4; ++i) {
    int idx = i * 256 + t;
    float4 g4 = ((const float4*)(gu + (size_t)row * RS_GU))[idx];
    float4 u4 = ((const float4*)(gu + (size_t)row * RS_GU + F))[idx];
    float4 r4;
    r4.x = g4.x / (1.0f + __expf(-g4.x)) * u4.x;
    r4.y = g4.y / (1.0f + __expf(-g4.y)) * u4.y;
    r4.z = g4.z / (1.0f + __expf(-g4.z)) * u4.z;
    r4.w = g4.w / (1.0f + __expf(-g4.w)) * u4.w;
    xs[idx * 4 + 0] = r4.x; xs[idx * 4 + 1] = r4.y; xs[idx * 4 + 2] = r4.z; xs[idx * 4 + 3] = r4.w;
    ushort4 o;
    o.x = f2bf(r4.x); o.y = f2bf(r4.y); o.z = f2bf(r4.z); o.w = f2bf(r4.w);
    ((ushort4*)(gbf + (size_t)row * F))[idx] = o;
  }
  if (t >= 16 && t < 64) t2e[(size_t)row * 64 + t] = 0;
  __syncthreads();
  int n = t & 15, g = t >> 4;
  float s = 0.0f;
  for (int k = g; k < F; k += 16) s = fmaf(xs[k], a[k * 16 + n], s);
  red[t] = s; __syncthreads();
  for (int h2 = 128; h2 >= 16; h2 >>= 1) { if (t < h2) red[t] += red[t + h2]; __syncthreads(); }
  if (t < 16) t2e[(size_t)row * 64 + t] = f2bf(LORA_SCALE * red[t]);
}

// ---------------- Build B-extension: bext[N][64], block-diagonal b^T ----------------
// bext[n][kk] = (kk>>4 == n>>logW) ? b_sel[kk&15][n & (W-1)] : 0
template <int NA>
__global__ void build_bext_kernel(Ptr3 bp, unsigned short* __restrict__ be, int logW) {
  int i = blockIdx.x * 256 + threadIdx.x;   // over N*64
  int n = i >> 6, kk = i & 63;
  int W = 1 << logW;
  int sel = n >> logW;
  float v = 0.0f;
  if ((kk >> 4) == sel && sel < NA)
    v = bp.p[sel][(size_t)(kk & 15) * W + (n & (W - 1))];
  be[i] = f2bf(v);
}

// ---------------- f32 [K,N] -> bf16 [N,K] transpose (64x64, vectorized) ----------------
__global__ __launch_bounds__(256) void transpose_bf16_kernel(const float* __restrict__ src,
                                      unsigned short* __restrict__ dst, int K, int N) {
  __shared__ unsigned short tile[64 * 68];
  int n0 = blockIdx.x * 64, k0 = blockIdx.y * 64;
  int t = threadIdx.x;
  int rr = t >> 4, c4 = (t & 15) << 2;
#pragma unroll
  for (int i = 0; i < 4; ++i) {
    int row = i * 16 + rr;
    float4 v = *(const float4*)(src + (size_t)(k0 + row) * N + n0 + c4);
    tile[(c4 + 0) * 68 + row] = f2bf(v.x);
    tile[(c4 + 1) * 68 + row] = f2bf(v.y);
    tile[(c4 + 2) * 68 + row] = f2bf(v.z);
    tile[(c4 + 3) * 68 + row] = f2bf(v.w);
  }
  __syncthreads();
#pragma unroll
  for (int i = 0; i < 4; ++i) {
    int row = i * 16 + rr;
    *(ushort4*)(dst + (size_t)(n0 + row) * K + k0 + c4) = *(const ushort4*)(tile + row * 68 + c4);
  }
}

// ---------------- bf16 MFMA GEMM, optional LoRA K-extension ----------------
// C = [C +] A @ Bt^T  [+ Ae @ Be^T]  where Ae:[M][64], Be:[N][64] (the rank-16 LoRA,
// scale pre-folded into Ae). A:[M,K] bf16, Bt:[N,K] bf16, C:[M,N] f32.
// XCD-chunked (m204 bijective) + M-inner decode: each XCD owns a contiguous N-range.
template <int BN, bool ACC, bool EXT>
__global__ __launch_bounds__(256) void gemm_bf16_kernel(
    const unsigned short* __restrict__ A, const unsigned short* __restrict__ Bt,
    float* __restrict__ C, int M, int N, int K,
    const unsigned short* __restrict__ Ae, const unsigned short* __restrict__ Be) {
  constexpr int WM = (BN == 128) ? 2 : 4;
  constexpr int RW = 128 / WM;
  constexpr int MI = RW / 16;
  constexpr int BCH = BN / 32;
  __shared__ __align__(16) unsigned short As[128 * 64];
  __shared__ __align__(16) unsigned short Bs[BN * 64];
  int t = threadIdx.x;
  int lane = t & 63, wave = t >> 6;
  int wr = (BN == 128) ? (wave >> 1) : wave;
  int wc = (BN == 128) ? (wave & 1) : 0;
  int MT = gridDim.y, NT = gridDim.x;
  int nwg = MT * NT;
  int orig = blockIdx.y * NT + blockIdx.x;
  int qq = nwg >> 3, rr8 = nwg & 7;
  int xcd = orig & 7, pos = orig >> 3;
  int wg = (xcd < rr8) ? (xcd * (qq + 1) + pos) : (rr8 * (qq + 1) + (xcd - rr8) * qq + pos);
  int m0 = (wg % MT) * 128, n0 = (wg / MT) * BN;
  int fr = lane & 15, fq = lane >> 4;
  f32x4 acc[MI][4] = {};
  int kIters = K / 64;
  int nIters = EXT ? kIters + 1 : kIters;
  for (int it = 0; it < nIters; ++it) {
    int k0 = it * 64;
    bool ext = EXT && (it == kIters);
#pragma unroll
    for (int c = 0; c < 4; ++c) {
      int i = c * 256 + t;
      int row = i >> 3, cc = i & 7;
      const unsigned short* src = ext ? (Ae + (size_t)(m0 + row) * 64 + cc * 8)
                                      : (A + (size_t)(m0 + row) * K + k0 + cc * 8);
      load_lds16(src, &As[i * 8]);
    }
#pragma unroll
    for (int c = 0; c < BCH; ++c) {
      int i = c * 256 + t;
      int row = i >> 3, cc = i & 7;
      const unsigned short* src = ext ? (Be + (size_t)(n0 + row) * 64 + cc * 8)
                                      : (Bt + (size_t)(n0 + row) * K + k0 + cc * 8);
      load_lds16(src, &Bs[i * 8]);
    }
    __syncthreads();
#pragma unroll
    for (int kk = 0; kk < 2; ++kk) {
      bf16x8 af[MI], bfr[4];
#pragma unroll
      for (int mi = 0; mi < MI; ++mi)
        af[mi] = *(const bf16x8*)(As + (wr * RW + mi * 16 + fr) * 64 + kk * 32 + fq * 8);
#pragma unroll
      for (int ni = 0; ni < 4; ++ni)
        bfr[ni] = *(const bf16x8*)(Bs + (wc * 64 + ni * 16 + fr) * 64 + kk * 32 + fq * 8);
#pragma unroll
      for (int mi = 0; mi < MI; ++mi)
#pragma unroll
        for (int ni = 0; ni < 4; ++ni)
          acc[mi][ni] = __builtin_amdgcn_mfma_f32_16x16x32_bf16(af[mi], bfr[ni], acc[mi][ni], 0, 0, 0);
    }
    __syncthreads();
  }
  // epilogue (C/D layout: col=lane&15, row=(lane>>4)*4+j)
#pragma unroll
  for (int mi = 0; mi < MI; ++mi)
#pragma unroll
    for (int ni = 0; ni < 4; ++ni)
#pragma unroll
      for (int j = 0; j < 4; ++j) {
        int r = m0 + wr * RW + mi * 16 + fq * 4 + j;
        int cl = n0 + wc * 64 + ni * 16 + fr;
        size_t idx = (size_t)r * N + cl;
        float v = acc[mi][ni][j];
        C[idx] = ACC ? C[idx] + v : v;
      }
}

// ---------------- RoPE apply in-place on fused qkv (q and k halves) ----------------
__global__ void rope_apply_qk_kernel(float* __restrict__ qkv, const float* __restrict__ cosb,
                                     const float* __restrict__ sinb) {
  int i = blockIdx.x * 256 + threadIdx.x;
  constexpr int total = B * S * H * 32;
  int which = (i >= total) ? 1 : 0;   // 0 = q, 1 = k
  int ii = i - which * total;
  int dh = ii & 31;
  int rest = ii >> 5;
  int hh = rest % H;
  int bs = rest / H;
  int s = bs % S;
  size_t base = (size_t)bs * RS_QKV + which * D + hh * DH;
  float x1 = qkv[base + dh], x2 = qkv[base + dh + 32];
  float c = cosb[s * DH + dh], sn = sinb[s * DH + dh];
  qkv[base + dh]      = x1 * c - x2 * sn;
  qkv[base + dh + 32] = x2 * c + x1 * sn;
}

// ---------------- Flash attention, bf16 MFMA ----------------
__global__ __launch_bounds__(256) void attn_mfma_kernel(
    const float* __restrict__ qkv, const int* __restrict__ amask,
    unsigned short* __restrict__ o) {
  __shared__ unsigned short Qs[64 * 72];
  __shared__ unsigned short Ks[64 * 72];
  __shared__ unsigned short Vt[64 * 72];   // [dh][key]
  __shared__ unsigned short Ps[4][16 * 72];
  __shared__ float msk[64];
  int bid = blockIdx.x;
  int qt = bid & 7, hh = (bid >> 3) & (H - 1), b = bid >> 7;
  int t = threadIdx.x;
  int lane = t & 63, w = t >> 6;
  int fr = lane & 15, fq = lane >> 4;
  int rr = t >> 4, c4 = (t & 15) << 2;
  size_t rowbase = (size_t)b * S;
  int q0 = qt * 64;
  const float scale = 0.125f;  // 1/sqrt(64)
#pragma unroll
  for (int i = 0; i < 4; ++i) {
    int row = i * 16 + rr;
    float4 v = *(const float4*)(qkv + (rowbase + q0 + row) * RS_QKV + hh * DH + c4);
    Qs[row * 72 + c4 + 0] = f2bf(v.x); Qs[row * 72 + c4 + 1] = f2bf(v.y);
    Qs[row * 72 + c4 + 2] = f2bf(v.z); Qs[row * 72 + c4 + 3] = f2bf(v.w);
  }
  f32x4 oacc[4] = {};
  float m_old[4] = {-1e30f, -1e30f, -1e30f, -1e30f};
  float l[4] = {};
  int qbase = q0 + w * 16;
  for (int kt = 0; kt <= qt; ++kt) {
    int kk0 = kt * 64;
#pragma unroll
    for (int i = 0; i < 4; ++i) {
      int row = i * 16 + rr;
      float4 kv = *(const float4*)(qkv + (rowbase + kk0 + row) * RS_QKV + D + hh * DH + c4);
      Ks[row * 72 + c4 + 0] = f2bf(kv.x); Ks[row * 72 + c4 + 1] = f2bf(kv.y);
      Ks[row * 72 + c4 + 2] = f2bf(kv.z); Ks[row * 72 + c4 + 3] = f2bf(kv.w);
      float4 vv = *(const float4*)(qkv + (rowbase + kk0 + row) * RS_QKV + 2 * D + hh * DH + c4);
      Vt[(c4 + 0) * 72 + row] = f2bf(vv.x); Vt[(c4 + 1) * 72 + row] = f2bf(vv.y);
      Vt[(c4 + 2) * 72 + row] = f2bf(vv.z); Vt[(c4 + 3) * 72 + row] = f2bf(vv.w);
    }
    if (t < 64) msk[t] = (amask[b * S + kk0 + t] > 0) ? 0.0f : -1e9f;
    __syncthreads();
    bf16x8 aq[2];
    aq[0] = *(const bf16x8*)(Qs + (w * 16 + fr) * 72 + fq * 8);
    aq[1] = *(const bf16x8*)(Qs + (w * 16 + fr) * 72 + 32 + fq * 8);
    f32x4 sacc[4];
#pragma unroll
    for (int ct = 0; ct < 4; ++ct) {
      bf16x8 bk0 = *(const bf16x8*)(Ks + (ct * 16 + fr) * 72 + fq * 8);
      bf16x8 bk1 = *(const bf16x8*)(Ks + (ct * 16 + fr) * 72 + 32 + fq * 8);
      f32x4 z = {};
      z = __builtin_amdgcn_mfma_f32_16x16x32_bf16(aq[0], bk0, z, 0, 0, 0);
      sacc[ct] = __builtin_amdgcn_mfma_f32_16x16x32_bf16(aq[1], bk1, z, 0, 0, 0);
    }
    float sv[4][4];
#pragma unroll
    for (int ct = 0; ct < 4; ++ct) {
      int kg = kk0 + ct * 16 + fr;
      float mk = msk[ct * 16 + fr];
#pragma unroll
      for (int j = 0; j < 4; ++j) {
        int qg = qbase + fq * 4 + j;
        float s = sacc[ct][j] * scale + mk;
        sv[ct][j] = (kg > qg) ? -1e9f : s;
      }
    }
    float mnew[4], f[4], rsum[4];
#pragma unroll
    for (int j = 0; j < 4; ++j) {
      float mt = fmaxf(fmaxf(sv[0][j], sv[1][j]), fmaxf(sv[2][j], sv[3][j]));
      for (int off = 1; off < 16; off <<= 1) mt = fmaxf(mt, __shfl_xor(mt, off));
      mnew[j] = fmaxf(m_old[j], mt);
      f[j] = __expf(m_old[j] - mnew[j]);
      float rs = 0.0f;
#pragma unroll
      for (int ct = 0; ct < 4; ++ct) {
        float e = __expf(sv[ct][j] - mnew[j]);
        sv[ct][j] = e;
        rs += e;
      }
      for (int off = 1; off < 16; off <<= 1) rs += __shfl_xor(rs, off);
      rsum[j] = rs;
      l[j] = l[j] * f[j] + rsum[j];
      m_old[j] = mnew[j];
#pragma unroll
      for (int dt = 0; dt < 4; ++dt) oacc[dt][j] *= f[j];
    }
#pragma unroll
    for (int ct = 0; ct < 4; ++ct)
#pragma unroll
      for (int j = 0; j < 4; ++j)
        Ps[w][(fq * 4 + j) * 72 + ct * 16 + fr] = f2bf(sv[ct][j]);
    __syncthreads();
    bf16x8 pa[2];
    pa[0] = *(const bf16x8*)(&Ps[w][fr * 72 + fq * 8]);
    pa[1] = *(const bf16x8*)(&Ps[w][fr * 72 + 32 + fq * 8]);
#pragma unroll
    for (int dt = 0; dt < 4; ++dt) {
      bf16x8 vb0 = *(const bf16x8*)(Vt + (dt * 16 + fr) * 72 + fq * 8);
      bf16x8 vb1 = *(const bf16x8*)(Vt + (dt * 16 + fr) * 72 + 32 + fq * 8);
      oacc[dt] = __builtin_amdgcn_mfma_f32_16x16x32_bf16(pa[0], vb0, oacc[dt], 0, 0, 0);
      oacc[dt] = __builtin_amdgcn_mfma_f32_16x16x32_bf16(pa[1], vb1, oacc[dt], 0, 0, 0);
    }
    __syncthreads();
  }
#pragma unroll
  for (int j = 0; j < 4; ++j) {
    float rinv = 1.0f / l[j];
    int qrow = qbase + fq * 4 + j;
#pragma unroll
    for (int dt = 0; dt < 4; ++dt)
      o[(rowbase + qrow) * D + hh * DH + dt * 16 + fr] = f2bf(oacc[dt][j] * rinv);
  }
}

// ---------------- Value head ----------------
__global__ void value_kernel(const unsigned short* __restrict__ hf, const float* __restrict__ vw,
                             const float* __restrict__ vb, float* __restrict__ out) {
  int row = blockIdx.x, t = threadIdx.x;
  float acc = 0.0f;
  for (int d = t; d < D; d += 256) acc = fmaf(bf2f(hf[(size_t)row * D + d]), vw[d], acc);
  __shared__ float red[256];
  red[t] = acc; __syncthreads();
  for (int s2 = 128; s2; s2 >>= 1) { if (t < s2) red[t] += red[t + s2]; __syncthreads(); }
  if (t == 0) out[row] = red[0] + vb[0];
}

extern "C" void kernel_launch(void* const* d_in, const int* in_sizes, int n_in,
                              void* d_out, int out_size, void* d_ws, size_t ws_size,
                              hipStream_t stream) {
  const int*   ids     = (const int*)d_in[0];
  const int*   amask   = (const int*)d_in[1];
  const float* emb     = (const float*)d_in[2];
  const float* ln1     = (const float*)d_in[3];
  const float* ln2     = (const float*)d_in[4];
  const float* wq = (const float*)d_in[5],  *aq = (const float*)d_in[6],  *bq = (const float*)d_in[7];
  const float* wk = (const float*)d_in[8],  *ak = (const float*)d_in[9],  *bk = (const float*)d_in[10];
  const float* wv = (const float*)d_in[11], *av = (const float*)d_in[12], *bv = (const float*)d_in[13];
  const float* wo = (const float*)d_in[14], *ao = (const float*)d_in[15], *bo = (const float*)d_in[16];
  const float* wg = (const float*)d_in[17], *ag = (const float*)d_in[18], *bg = (const float*)d_in[19];
  const float* wu = (const float*)d_in[20], *au = (const float*)d_in[21], *bu = (const float*)d_in[22];
  const float* wd = (const float*)d_in[23], *ad = (const float*)d_in[24], *bd = (const float*)d_in[25];
  const float* final_ln  = (const float*)d_in[26];
  const float* lm_head_w = (const float*)d_in[27];
  const float* value_w   = (const float*)d_in[28];
  const float* value_b   = (const float*)d_in[29];

  float* out    = (float*)d_out;
  float* logits = out;
  float* values = out + (size_t)BS * V;

  // ---- workspace ----
  float* Wf = (float*)d_ws;
  float* cosb = Wf; Wf += S * DH;
  float* sinb = Wf; Wf += S * DH;
  float* h    = Wf; Wf += (size_t)BS * D;
  float* qkv  = Wf; Wf += (size_t)BS * RS_QKV;
  float* gu   = Wf; Wf += (size_t)BS * RS_GU;
  unsigned short* Wb = (unsigned short*)Wf;
  unsigned short* x_bf  = Wb; Wb += (size_t)BS * D;
  unsigned short* t2e   = Wb; Wb += (size_t)BS * 64;
  unsigned short* wqkvT = Wb; Wb += (size_t)L * 3 * D * D;
  unsigned short* woT   = Wb; Wb += (size_t)L * D * D;
  unsigned short* wguT  = Wb; Wb += (size_t)L * 2 * D * F;
  unsigned short* wdT   = Wb; Wb += (size_t)L * F * D;
  unsigned short* lmT   = Wb; Wb += (size_t)D * V;
  unsigned short* beQKV = Wb; Wb += (size_t)L * 3 * D * 64;
  unsigned short* beO   = Wb; Wb += (size_t)L * D * 64;
  unsigned short* beGU  = Wb; Wb += (size_t)L * 2 * F * 64;
  unsigned short* beD   = Wb; Wb += (size_t)L * D * 64;
  // aliases into dead regions
  unsigned short* obf = (unsigned short*)gu;   // [BS][D] bf16 inside gu (dead during attn->wo)
  unsigned short* gbf = (unsigned short*)qkv;  // [BS][F] bf16 inside qkv (dead after attn)

  // ---- weight transposes (bf16 [N,K]) + LoRA B-extensions, every call ----
  auto T = [&](const float* src, unsigned short* dst, int K_, int N_) {
    transpose_bf16_kernel<<<dim3(N_ / 64, K_ / 64), 256, 0, stream>>>(src, dst, K_, N_);
  };
  for (int l = 0; l < L; ++l) {
    size_t DD = (size_t)D * D, DF = (size_t)D * F;
    size_t oRD = (size_t)l * R * D, oRF = (size_t)l * R * F;
    T(wq + l * DD, wqkvT + (size_t)l * 3 * DD, D, D);
    T(wk + l * DD, wqkvT + (size_t)l * 3 * DD + DD, D, D);
    T(wv + l * DD, wqkvT + (size_t)l * 3 * DD + 2 * DD, D, D);
    T(wo + l * DD, woT + l * DD, D, D);
    T(wg + l * DF, wguT + (size_t)l * 2 * DF, D, F);
    T(wu + l * DF, wguT + (size_t)l * 2 * DF + DF, D, F);
    T(wd + l * DF, wdT + l * DF, F, D);
    { Ptr3 bp = {{bq + oRD, bk + oRD, bv + oRD}};
      build_bext_kernel<3><<<dim3(3 * D * 64 / 256), 256, 0, stream>>>(bp, beQKV + (size_t)l * 3 * D * 64, 10); }
    { Ptr3 bp = {{bo + oRD, nullptr, nullptr}};
      build_bext_kernel<1><<<dim3(D * 64 / 256), 256, 0, stream>>>(bp, beO + (size_t)l * D * 64, 10); }
    { Ptr3 bp = {{bg + oRF, bu + oRF, nullptr}};
      build_bext_kernel<2><<<dim3(2 * F * 64 / 256), 256, 0, stream>>>(bp, beGU + (size_t)l * 2 * F * 64, 12); }
    { Ptr3 bp = {{bd + oRD, nullptr, nullptr}};
      build_bext_kernel<1><<<dim3(D * 64 / 256), 256, 0, stream>>>(bp, beD + (size_t)l * D * 64, 10); }
  }
  T(lm_head_w, lmT, D, V);

  rope_cache_kernel<<<dim3(S), dim3(32), 0, stream>>>(cosb, sinb);
  embed_kernel<<<dim3(BS), dim3(256), 0, stream>>>(ids, emb, h);

  constexpr int ROPE_BLOCKS = (B * S * H * 32 + 255) / 256;

  for (int l = 0; l < L; ++l) {
    size_t DD = (size_t)D * D, DF = (size_t)D * F;
    size_t oDR = (size_t)l * D * R, oFR = (size_t)l * F * R;

    // ---- attention block ----
    { Ptr3 ap = {{aq + oDR, ak + oDR, av + oDR}};
      rms_lora_kernel<3><<<dim3(BS), 256, 0, stream>>>(h, ln1 + (size_t)l * D, ap, x_bf, t2e); }
    gemm_bf16_kernel<128, false, true><<<dim3(3 * D / 128, BS / 128), 256, 0, stream>>>(
        x_bf, wqkvT + (size_t)l * 3 * DD, qkv, BS, 3 * D, D, t2e, beQKV + (size_t)l * 3 * D * 64);
    rope_apply_qk_kernel<<<dim3(2 * ROPE_BLOCKS), 256, 0, stream>>>(qkv, cosb, sinb);

    attn_mfma_kernel<<<dim3(B * H * (S / 64)), 256, 0, stream>>>(qkv, amask, obf);

    lora_o_kernel<<<dim3(BS), 256, 0, stream>>>(obf, ao + oDR, t2e);
    gemm_bf16_kernel<64, true, true><<<dim3(D / 64, BS / 128), 256, 0, stream>>>(
        obf, woT + l * DD, h, BS, D, D, t2e, beO + (size_t)l * D * 64);

    // ---- MLP block ----
    { Ptr3 ap = {{ag + oDR, au + oDR, nullptr}};
      rms_lora_kernel<2><<<dim3(BS), 256, 0, stream>>>(h, ln2 + (size_t)l * D, ap, x_bf, t2e); }
    gemm_bf16_kernel<128, false, true><<<dim3(2 * F / 128, BS / 128), 256, 0, stream>>>(
        x_bf, wguT + (size_t)l * 2 * DF, gu, BS, 2 * F, D, t2e, beGU + (size_t)l * 2 * F * 64);

    silu_lora_kernel<<<dim3(BS), 256, 0, stream>>>(gu, ad + oFR, gbf, t2e);

    gemm_bf16_kernel<64, true, true><<<dim3(D / 64, BS / 128), 256, 0, stream>>>(
        gbf, wdT + l * DF, h, BS, D, F, t2e, beD + (size_t)l * D * 64);
  }

  // ---- final norm + heads ----
  rmsnorm_bf16_kernel<<<dim3(BS), 256, 0, stream>>>(h, final_ln, x_bf);
  gemm_bf16_kernel<128, false, false><<<dim3(V / 128, BS / 128), 256, 0, stream>>>(
      x_bf, lmT, logits, BS, V, D, nullptr, nullptr);
  value_kernel<<<dim3(BS), 256, 0, stream>>>(x_bf, value_w, value_b, values);
}

// Round 6
// 1137.264 us; speedup vs baseline: 1.2208x; 1.0230x over previous
//
#include <hip/hip_runtime.h>
#include <math.h>

// LLaMA-style decoder forward: B=2 S=512 D=1024 H=16 F=4096 V=32000 L=2 R=16
constexpr int B = 2, S = 512, D = 1024, H = 16, F = 4096, V = 32000, L = 2, R = 16, DH = 64;
constexpr int BS = B * S;          // 1024 rows
constexpr float LORA_SCALE = 2.0f; // alpha/r
constexpr float EPS = 1e-5f;
constexpr int RS_QKV = 3 * D;      // fused qkv row stride
constexpr int RS_GU  = 2 * F;      // fused g|u row stride

typedef __attribute__((ext_vector_type(8))) __bf16 bf16x8;
typedef __attribute__((ext_vector_type(4))) float f32x4;

__device__ __forceinline__ unsigned short f2bf(float f) {
  unsigned u = __builtin_bit_cast(unsigned, f);
  unsigned r = (u + 0x7FFFu + ((u >> 16) & 1u)) >> 16;  // RNE
  return (unsigned short)r;
}
__device__ __forceinline__ float bf2f(unsigned short us) {
  return __builtin_bit_cast(float, (unsigned)us << 16);
}
__device__ __forceinline__ void load_lds16(const void* g, void* l) {
  __builtin_amdgcn_global_load_lds((const __attribute__((address_space(1))) void*)g,
                                   (__attribute__((address_space(3))) void*)l, 16, 0, 0);
}

struct Ptr3 { const float* p[3]; };

// ---------------- RoPE cache ----------------
__global__ void rope_cache_kernel(float* __restrict__ cosb, float* __restrict__ sinb) {
  int s = blockIdx.x, j = threadIdx.x;  // j in [0,32)
  float inv = __expf(-(float)j * (9.210340371976184f / 32.0f));
  float ang = (float)s * inv;
  float c = cosf(ang), sn = sinf(ang);
  cosb[s * DH + j] = c;  cosb[s * DH + j + 32] = c;
  sinb[s * DH + j] = sn; sinb[s * DH + j + 32] = sn;
}

// ---------------- Embedding gather ----------------
__global__ void embed_kernel(const int* __restrict__ ids, const float* __restrict__ emb,
                             float* __restrict__ h) {
  int row = blockIdx.x, t = threadIdx.x;
  int id = ids[row];
  ((float4*)(h + (size_t)row * D))[t] = ((const float4*)(emb + (size_t)id * D))[t];
}

// ---------------- RMSNorm -> bf16 (final norm, no LoRA) ----------------
__global__ void rmsnorm_bf16_kernel(const float* __restrict__ x, const float* __restrict__ w,
                                    unsigned short* __restrict__ y) {
  int row = blockIdx.x, t = threadIdx.x;
  float4 xv = ((const float4*)(x + (size_t)row * D))[t];
  float ss = xv.x * xv.x + xv.y * xv.y + xv.z * xv.z + xv.w * xv.w;
  __shared__ float red[256];
  red[t] = ss; __syncthreads();
  for (int s2 = 128; s2; s2 >>= 1) { if (t < s2) red[t] += red[t + s2]; __syncthreads(); }
  float rinv = rsqrtf(red[0] * (1.0f / D) + EPS);
  float4 wv = ((const float4*)w)[t];
  ushort4 o;
  o.x = f2bf(xv.x * rinv * wv.x); o.y = f2bf(xv.y * rinv * wv.y);
  o.z = f2bf(xv.z * rinv * wv.z); o.w = f2bf(xv.w * rinv * wv.w);
  ((ushort4*)(y + (size_t)row * D))[t] = o;
}

// ---------------- Fused RMSNorm + LoRA down-proj: x_bf + t2e[row][64] ----------------
template <int NA>
__global__ void rms_lora_kernel(const float* __restrict__ hp, const float* __restrict__ w,
                                Ptr3 ap, unsigned short* __restrict__ xbf,
                                unsigned short* __restrict__ t2e) {
  int row = blockIdx.x, t = threadIdx.x;  // 256 threads
  __shared__ float xs[D];
  __shared__ float red[256];
  float4 xv = ((const float4*)(hp + (size_t)row * D))[t];
  float ss = xv.x * xv.x + xv.y * xv.y + xv.z * xv.z + xv.w * xv.w;
  red[t] = ss; __syncthreads();
  for (int s2 = 128; s2; s2 >>= 1) { if (t < s2) red[t] += red[t + s2]; __syncthreads(); }
  float rinv = rsqrtf(red[0] * (1.0f / D) + EPS);
  float4 wv = ((const float4*)w)[t];
  float4 nx;
  nx.x = xv.x * rinv * wv.x; nx.y = xv.y * rinv * wv.y;
  nx.z = xv.z * rinv * wv.z; nx.w = xv.w * rinv * wv.w;
  xs[t * 4 + 0] = nx.x; xs[t * 4 + 1] = nx.y; xs[t * 4 + 2] = nx.z; xs[t * 4 + 3] = nx.w;
  ushort4 o;
  o.x = f2bf(nx.x); o.y = f2bf(nx.y); o.z = f2bf(nx.z); o.w = f2bf(nx.w);
  ((ushort4*)(xbf + (size_t)row * D))[t] = o;
  if (t >= NA * 16 && t < 64) t2e[(size_t)row * 64 + t] = 0;
  __syncthreads();
  int n = t & 15, g = t >> 4;
#pragma unroll
  for (int ad = 0; ad < NA; ++ad) {
    const float* a = ap.p[ad];
    float s = 0.0f;
    for (int k = g; k < D; k += 16) s = fmaf(xs[k], a[k * 16 + n], s);
    red[t] = s; __syncthreads();
    for (int h2 = 128; h2 >= 16; h2 >>= 1) { if (t < h2) red[t] += red[t + h2]; __syncthreads(); }
    if (t < 16) t2e[(size_t)row * 64 + ad * 16 + t] = f2bf(LORA_SCALE * red[t]);
    __syncthreads();
  }
}

// ---------------- LoRA down-proj from bf16 activation (o-proj) ----------------
__global__ void lora_o_kernel(const unsigned short* __restrict__ xb, const float* __restrict__ a,
                              unsigned short* __restrict__ t2e) {
  int row = blockIdx.x, t = threadIdx.x;  // 256 threads, K=D
  __shared__ float xs[D];
  __shared__ float red[256];
  for (int k = t; k < D; k += 256) xs[k] = bf2f(xb[(size_t)row * D + k]);
  if (t >= 16 && t < 64) t2e[(size_t)row * 64 + t] = 0;
  __syncthreads();
  int n = t & 15, g = t >> 4;
  float s = 0.0f;
  for (int k = g; k < D; k += 16) s = fmaf(xs[k], a[k * 16 + n], s);
  red[t] = s; __syncthreads();
  for (int h2 = 128; h2 >= 16; h2 >>= 1) { if (t < h2) red[t] += red[t + h2]; __syncthreads(); }
  if (t < 16) t2e[(size_t)row * 64 + t] = f2bf(LORA_SCALE * red[t]);
}

// ---------------- Fused SwiGLU + LoRA down-proj: gbf + t2e ----------------
__global__ void silu_lora_kernel(const float* __restrict__ gu, const float* __restrict__ a,
                                 unsigned short* __restrict__ gbf, unsigned short* __restrict__ t2e) {
  int row = blockIdx.x, t = threadIdx.x;  // 256 threads
  __shared__ float xs[F];   // 16KB
  __shared__ float red[256];
#pragma unroll
  for (int i = 0; i < 4; ++i) {
    int idx = i * 256 + t;
    float4 g4 = ((const float4*)(gu + (size_t)row * RS_GU))[idx];
    float4 u4 = ((const float4*)(gu + (size_t)row * RS_GU + F))[idx];
    float4 r4;
    r4.x = g4.x / (1.0f + __expf(-g4.x)) * u4.x;
    r4.y = g4.y / (1.0f + __expf(-g4.y)) * u4.y;
    r4.z = g4.z / (1.0f + __expf(-g4.z)) * u4.z;
    r4.w = g4.w / (1.0f + __expf(-g4.w)) * u4.w;
    xs[idx * 4 + 0] = r4.x; xs[idx * 4 + 1] = r4.y; xs[idx * 4 + 2] = r4.z; xs[idx * 4 + 3] = r4.w;
    ushort4 o;
    o.x = f2bf(r4.x); o.y = f2bf(r4.y); o.z = f2bf(r4.z); o.w = f2bf(r4.w);
    ((ushort4*)(gbf + (size_t)row * F))[idx] = o;
  }
  if (t >= 16 && t < 64) t2e[(size_t)row * 64 + t] = 0;
  __syncthreads();
  int n = t & 15, g = t >> 4;
  float s = 0.0f;
  for (int k = g; k < F; k += 16) s = fmaf(xs[k], a[k * 16 + n], s);
  red[t] = s; __syncthreads();
  for (int h2 = 128; h2 >= 16; h2 >>= 1) { if (t < h2) red[t] += red[t + h2]; __syncthreads(); }
  if (t < 16) t2e[(size_t)row * 64 + t] = f2bf(LORA_SCALE * red[t]);
}

// ---------------- Build B-extension: bext[N][64], block-diagonal b^T ----------------
template <int NA>
__global__ void build_bext_kernel(Ptr3 bp, unsigned short* __restrict__ be, int logW) {
  int i = blockIdx.x * 256 + threadIdx.x;   // over N*64
  int n = i >> 6, kk = i & 63;
  int W = 1 << logW;
  int sel = n >> logW;
  float v = 0.0f;
  if ((kk >> 4) == sel && sel < NA)
    v = bp.p[sel][(size_t)(kk & 15) * W + (n & (W - 1))];
  be[i] = f2bf(v);
}

// ---------------- f32 [K,N] -> bf16 [N,K] transpose (64x64, vectorized) ----------------
__global__ __launch_bounds__(256) void transpose_bf16_kernel(const float* __restrict__ src,
                                      unsigned short* __restrict__ dst, int K, int N) {
  __shared__ unsigned short tile[64 * 68];
  int n0 = blockIdx.x * 64, k0 = blockIdx.y * 64;
  int t = threadIdx.x;
  int rr = t >> 4, c4 = (t & 15) << 2;
#pragma unroll
  for (int i = 0; i < 4; ++i) {
    int row = i * 16 + rr;
    float4 v = *(const float4*)(src + (size_t)(k0 + row) * N + n0 + c4);
    tile[(c4 + 0) * 68 + row] = f2bf(v.x);
    tile[(c4 + 1) * 68 + row] = f2bf(v.y);
    tile[(c4 + 2) * 68 + row] = f2bf(v.z);
    tile[(c4 + 3) * 68 + row] = f2bf(v.w);
  }
  __syncthreads();
#pragma unroll
  for (int i = 0; i < 4; ++i) {
    int row = i * 16 + rr;
    *(ushort4*)(dst + (size_t)(n0 + row) * K + k0 + c4) = *(const ushort4*)(tile + row * 68 + c4);
  }
}

// ---------------- bf16 MFMA GEMM, depth-2 double-buffered pipeline + LoRA K-ext ----------------
// C = [C +] A @ Bt^T [+ Ae @ Be^T].  A:[M,K] bf16, Bt:[N,K] bf16, C:[M,N] f32.
// Pipeline (T3 recipe, depth 2): STAGE(t),STAGE(t+1) prologue; per iter
// vmcnt(LOADS)->barrier->MFMA(buf)->barrier->STAGE(t+2). Counted vmcnt keeps the
// next tile's loads in flight across the compute phase (never drains to 0 mid-loop).
template <int BN, bool ACC, bool EXT>
__global__ __launch_bounds__(256) void gemm_bf16_kernel(
    const unsigned short* __restrict__ A, const unsigned short* __restrict__ Bt,
    float* __restrict__ C, int M, int N, int K,
    const unsigned short* __restrict__ Ae, const unsigned short* __restrict__ Be) {
  constexpr int WM = (BN == 128) ? 2 : 4;
  constexpr int RW = 128 / WM;
  constexpr int MI = RW / 16;
  constexpr int BCH = BN / 32;
  __shared__ __align__(16) unsigned short As[2][128 * 64];
  __shared__ __align__(16) unsigned short Bs[2][BN * 64];
  int t = threadIdx.x;
  int lane = t & 63, wave = t >> 6;
  int wr = (BN == 128) ? (wave >> 1) : wave;
  int wc = (BN == 128) ? (wave & 1) : 0;
  int MT = gridDim.y, NT = gridDim.x;
  int nwg = MT * NT;
  int orig = blockIdx.y * NT + blockIdx.x;
  int qq = nwg >> 3, rr8 = nwg & 7;
  int xcd = orig & 7, pos = orig >> 3;
  int wg = (xcd < rr8) ? (xcd * (qq + 1) + pos) : (rr8 * (qq + 1) + (xcd - rr8) * qq + pos);
  int m0 = (wg % MT) * 128, n0 = (wg / MT) * BN;
  int fr = lane & 15, fq = lane >> 4;
  f32x4 acc[MI][4] = {};
  int kIters = K / 64;
  int nIters = EXT ? kIters + 1 : kIters;

  auto STAGE = [&](int it, int buf) {
    bool ext = EXT && (it == kIters);
    int k0 = it * 64;
#pragma unroll
    for (int c = 0; c < 4; ++c) {
      int i = c * 256 + t;
      int row = i >> 3, cc = i & 7;
      const unsigned short* src = ext ? (Ae + (size_t)(m0 + row) * 64 + cc * 8)
                                      : (A + (size_t)(m0 + row) * K + k0 + cc * 8);
      load_lds16(src, &As[buf][i * 8]);
    }
#pragma unroll
    for (int c = 0; c < BCH; ++c) {
      int i = c * 256 + t;
      int row = i >> 3, cc = i & 7;
      const unsigned short* src = ext ? (Be + (size_t)(n0 + row) * 64 + cc * 8)
                                      : (Bt + (size_t)(n0 + row) * K + k0 + cc * 8);
      load_lds16(src, &Bs[buf][i * 8]);
    }
  };

  STAGE(0, 0);
  if (nIters > 1) STAGE(1, 1);
  int cur = 0;
  for (int it = 0; it < nIters; ++it) {
    if (it + 1 < nIters) {
      // wait for buf[cur]'s loads; the LOADS newer ops (next tile) stay in flight
      if constexpr (BN == 128) asm volatile("s_waitcnt vmcnt(8)" ::: "memory");
      else                     asm volatile("s_waitcnt vmcnt(6)" ::: "memory");
    } else {
      asm volatile("s_waitcnt vmcnt(0)" ::: "memory");
    }
    __builtin_amdgcn_s_barrier();
#pragma unroll
    for (int kk = 0; kk < 2; ++kk) {
      bf16x8 af[MI], bfr[4];
#pragma unroll
      for (int mi = 0; mi < MI; ++mi)
        af[mi] = *(const bf16x8*)(&As[cur][(wr * RW + mi * 16 + fr) * 64 + kk * 32 + fq * 8]);
#pragma unroll
      for (int ni = 0; ni < 4; ++ni)
        bfr[ni] = *(const bf16x8*)(&Bs[cur][(wc * 64 + ni * 16 + fr) * 64 + kk * 32 + fq * 8]);
#pragma unroll
      for (int mi = 0; mi < MI; ++mi)
#pragma unroll
        for (int ni = 0; ni < 4; ++ni)
          acc[mi][ni] = __builtin_amdgcn_mfma_f32_16x16x32_bf16(af[mi], bfr[ni], acc[mi][ni], 0, 0, 0);
    }
    __builtin_amdgcn_s_barrier();   // all waves done reading buf[cur] (lgkm drained before MFMA)
    if (it + 2 < nIters) STAGE(it + 2, cur);
    cur ^= 1;
  }
  // epilogue (C/D layout: col=lane&15, row=(lane>>4)*4+j)
#pragma unroll
  for (int mi = 0; mi < MI; ++mi)
#pragma unroll
    for (int ni = 0; ni < 4; ++ni)
#pragma unroll
      for (int j = 0; j < 4; ++j) {
        int r = m0 + wr * RW + mi * 16 + fq * 4 + j;
        int cl = n0 + wc * 64 + ni * 16 + fr;
        size_t idx = (size_t)r * N + cl;
        float v = acc[mi][ni][j];
        C[idx] = ACC ? C[idx] + v : v;
      }
}

// ---------------- RoPE apply in-place on fused qkv (q and k halves) ----------------
__global__ void rope_apply_qk_kernel(float* __restrict__ qkv, const float* __restrict__ cosb,
                                     const float* __restrict__ sinb) {
  int i = blockIdx.x * 256 + threadIdx.x;
  constexpr int total = B * S * H * 32;
  int which = (i >= total) ? 1 : 0;   // 0 = q, 1 = k
  int ii = i - which * total;
  int dh = ii & 31;
  int rest = ii >> 5;
  int hh = rest % H;
  int bs = rest / H;
  int s = bs % S;
  size_t base = (size_t)bs * RS_QKV + which * D + hh * DH;
  float x1 = qkv[base + dh], x2 = qkv[base + dh + 32];
  float c = cosb[s * DH + dh], sn = sinb[s * DH + dh];
  qkv[base + dh]      = x1 * c - x2 * sn;
  qkv[base + dh + 32] = x2 * c + x1 * sn;
}

// ---------------- Flash attention, bf16 MFMA ----------------
__global__ __launch_bounds__(256) void attn_mfma_kernel(
    const float* __restrict__ qkv, const int* __restrict__ amask,
    unsigned short* __restrict__ o) {
  __shared__ unsigned short Qs[64 * 72];
  __shared__ unsigned short Ks[64 * 72];
  __shared__ unsigned short Vt[64 * 72];   // [dh][key]
  __shared__ unsigned short Ps[4][16 * 72];
  __shared__ float msk[64];
  int bid = blockIdx.x;
  int qt = bid & 7, hh = (bid >> 3) & (H - 1), b = bid >> 7;
  int t = threadIdx.x;
  int lane = t & 63, w = t >> 6;
  int fr = lane & 15, fq = lane >> 4;
  int rr = t >> 4, c4 = (t & 15) << 2;
  size_t rowbase = (size_t)b * S;
  int q0 = qt * 64;
  const float scale = 0.125f;  // 1/sqrt(64)
#pragma unroll
  for (int i = 0; i < 4; ++i) {
    int row = i * 16 + rr;
    float4 v = *(const float4*)(qkv + (rowbase + q0 + row) * RS_QKV + hh * DH + c4);
    Qs[row * 72 + c4 + 0] = f2bf(v.x); Qs[row * 72 + c4 + 1] = f2bf(v.y);
    Qs[row * 72 + c4 + 2] = f2bf(v.z); Qs[row * 72 + c4 + 3] = f2bf(v.w);
  }
  f32x4 oacc[4] = {};
  float m_old[4] = {-1e30f, -1e30f, -1e30f, -1e30f};
  float l[4] = {};
  int qbase = q0 + w * 16;
  for (int kt = 0; kt <= qt; ++kt) {
    int kk0 = kt * 64;
#pragma unroll
    for (int i = 0; i < 4; ++i) {
      int row = i * 16 + rr;
      float4 kv = *(const float4*)(qkv + (rowbase + kk0 + row) * RS_QKV + D + hh * DH + c4);
      Ks[row * 72 + c4 + 0] = f2bf(kv.x); Ks[row * 72 + c4 + 1] = f2bf(kv.y);
      Ks[row * 72 + c4 + 2] = f2bf(kv.z); Ks[row * 72 + c4 + 3] = f2bf(kv.w);
      float4 vv = *(const float4*)(qkv + (rowbase + kk0 + row) * RS_QKV + 2 * D + hh * DH + c4);
      Vt[(c4 + 0) * 72 + row] = f2bf(vv.x); Vt[(c4 + 1) * 72 + row] = f2bf(vv.y);
      Vt[(c4 + 2) * 72 + row] = f2bf(vv.z); Vt[(c4 + 3) * 72 + row] = f2bf(vv.w);
    }
    if (t < 64) msk[t] = (amask[b * S + kk0 + t] > 0) ? 0.0f : -1e9f;
    __syncthreads();
    bf16x8 aq[2];
    aq[0] = *(const bf16x8*)(Qs + (w * 16 + fr) * 72 + fq * 8);
    aq[1] = *(const bf16x8*)(Qs + (w * 16 + fr) * 72 + 32 + fq * 8);
    f32x4 sacc[4];
#pragma unroll
    for (int ct = 0; ct < 4; ++ct) {
      bf16x8 bk0 = *(const bf16x8*)(Ks + (ct * 16 + fr) * 72 + fq * 8);
      bf16x8 bk1 = *(const bf16x8*)(Ks + (ct * 16 + fr) * 72 + 32 + fq * 8);
      f32x4 z = {};
      z = __builtin_amdgcn_mfma_f32_16x16x32_bf16(aq[0], bk0, z, 0, 0, 0);
      sacc[ct] = __builtin_amdgcn_mfma_f32_16x16x32_bf16(aq[1], bk1, z, 0, 0, 0);
    }
    float sv[4][4];
#pragma unroll
    for (int ct = 0; ct < 4; ++ct) {
      int kg = kk0 + ct * 16 + fr;
      float mk = msk[ct * 16 + fr];
#pragma unroll
      for (int j = 0; j < 4; ++j) {
        int qg = qbase + fq * 4 + j;
        float s = sacc[ct][j] * scale + mk;
        sv[ct][j] = (kg > qg) ? -1e9f : s;
      }
    }
    float mnew[4], f[4], rsum[4];
#pragma unroll
    for (int j = 0; j < 4; ++j) {
      float mt = fmaxf(fmaxf(sv[0][j], sv[1][j]), fmaxf(sv[2][j], sv[3][j]));
      for (int off = 1; off < 16; off <<= 1) mt = fmaxf(mt, __shfl_xor(mt, off));
      mnew[j] = fmaxf(m_old[j], mt);
      f[j] = __expf(m_old[j] - mnew[j]);
      float rs = 0.0f;
#pragma unroll
      for (int ct = 0; ct < 4; ++ct) {
        float e = __expf(sv[ct][j] - mnew[j]);
        sv[ct][j] = e;
        rs += e;
      }
      for (int off = 1; off < 16; off <<= 1) rs += __shfl_xor(rs, off);
      rsum[j] = rs;
      l[j] = l[j] * f[j] + rsum[j];
      m_old[j] = mnew[j];
#pragma unroll
      for (int dt = 0; dt < 4; ++dt) oacc[dt][j] *= f[j];
    }
#pragma unroll
    for (int ct = 0; ct < 4; ++ct)
#pragma unroll
      for (int j = 0; j < 4; ++j)
        Ps[w][(fq * 4 + j) * 72 + ct * 16 + fr] = f2bf(sv[ct][j]);
    __syncthreads();
    bf16x8 pa[2];
    pa[0] = *(const bf16x8*)(&Ps[w][fr * 72 + fq * 8]);
    pa[1] = *(const bf16x8*)(&Ps[w][fr * 72 + 32 + fq * 8]);
#pragma unroll
    for (int dt = 0; dt < 4; ++dt) {
      bf16x8 vb0 = *(const bf16x8*)(Vt + (dt * 16 + fr) * 72 + fq * 8);
      bf16x8 vb1 = *(const bf16x8*)(Vt + (dt * 16 + fr) * 72 + 32 + fq * 8);
      oacc[dt] = __builtin_amdgcn_mfma_f32_16x16x32_bf16(pa[0], vb0, oacc[dt], 0, 0, 0);
      oacc[dt] = __builtin_amdgcn_mfma_f32_16x16x32_bf16(pa[1], vb1, oacc[dt], 0, 0, 0);
    }
    __syncthreads();
  }
#pragma unroll
  for (int j = 0; j < 4; ++j) {
    float rinv = 1.0f / l[j];
    int qrow = qbase + fq * 4 + j;
#pragma unroll
    for (int dt = 0; dt < 4; ++dt)
      o[(rowbase + qrow) * D + hh * DH + dt * 16 + fr] = f2bf(oacc[dt][j] * rinv);
  }
}

// ---------------- Value head ----------------
__global__ void value_kernel(const unsigned short* __restrict__ hf, const float* __restrict__ vw,
                             const float* __restrict__ vb, float* __restrict__ out) {
  int row = blockIdx.x, t = threadIdx.x;
  float acc = 0.0f;
  for (int d = t; d < D; d += 256) acc = fmaf(bf2f(hf[(size_t)row * D + d]), vw[d], acc);
  __shared__ float red[256];
  red[t] = acc; __syncthreads();
  for (int s2 = 128; s2; s2 >>= 1) { if (t < s2) red[t] += red[t + s2]; __syncthreads(); }
  if (t == 0) out[row] = red[0] + vb[0];
}

extern "C" void kernel_launch(void* const* d_in, const int* in_sizes, int n_in,
                              void* d_out, int out_size, void* d_ws, size_t ws_size,
                              hipStream_t stream) {
  const int*   ids     = (const int*)d_in[0];
  const int*   amask   = (const int*)d_in[1];
  const float* emb     = (const float*)d_in[2];
  const float* ln1     = (const float*)d_in[3];
  const float* ln2     = (const float*)d_in[4];
  const float* wq = (const float*)d_in[5],  *aq = (const float*)d_in[6],  *bq = (const float*)d_in[7];
  const float* wk = (const float*)d_in[8],  *ak = (const float*)d_in[9],  *bk = (const float*)d_in[10];
  const float* wv = (const float*)d_in[11], *av = (const float*)d_in[12], *bv = (const float*)d_in[13];
  const float* wo = (const float*)d_in[14], *ao = (const float*)d_in[15], *bo = (const float*)d_in[16];
  const float* wg = (const float*)d_in[17], *ag = (const float*)d_in[18], *bg = (const float*)d_in[19];
  const float* wu = (const float*)d_in[20], *au = (const float*)d_in[21], *bu = (const float*)d_in[22];
  const float* wd = (const float*)d_in[23], *ad = (const float*)d_in[24], *bd = (const float*)d_in[25];
  const float* final_ln  = (const float*)d_in[26];
  const float* lm_head_w = (const float*)d_in[27];
  const float* value_w   = (const float*)d_in[28];
  const float* value_b   = (const float*)d_in[29];

  float* out    = (float*)d_out;
  float* logits = out;
  float* values = out + (size_t)BS * V;

  // ---- workspace ----
  float* Wf = (float*)d_ws;
  float* cosb = Wf; Wf += S * DH;
  float* sinb = Wf; Wf += S * DH;
  float* h    = Wf; Wf += (size_t)BS * D;
  float* qkv  = Wf; Wf += (size_t)BS * RS_QKV;
  float* gu   = Wf; Wf += (size_t)BS * RS_GU;
  unsigned short* Wb = (unsigned short*)Wf;
  unsigned short* x_bf  = Wb; Wb += (size_t)BS * D;
  unsigned short* t2e   = Wb; Wb += (size_t)BS * 64;
  unsigned short* wqkvT = Wb; Wb += (size_t)L * 3 * D * D;
  unsigned short* woT   = Wb; Wb += (size_t)L * D * D;
  unsigned short* wguT  = Wb; Wb += (size_t)L * 2 * D * F;
  unsigned short* wdT   = Wb; Wb += (size_t)L * F * D;
  unsigned short* lmT   = Wb; Wb += (size_t)D * V;
  unsigned short* beQKV = Wb; Wb += (size_t)L * 3 * D * 64;
  unsigned short* beO   = Wb; Wb += (size_t)L * D * 64;
  unsigned short* beGU  = Wb; Wb += (size_t)L * 2 * F * 64;
  unsigned short* beD   = Wb; Wb += (size_t)L * D * 64;
  // aliases into dead regions
  unsigned short* obf = (unsigned short*)gu;   // [BS][D] bf16 inside gu (dead during attn->wo)
  unsigned short* gbf = (unsigned short*)qkv;  // [BS][F] bf16 inside qkv (dead after attn)

  // ---- weight transposes (bf16 [N,K]) + LoRA B-extensions, every call ----
  auto T = [&](const float* src, unsigned short* dst, int K_, int N_) {
    transpose_bf16_kernel<<<dim3(N_ / 64, K_ / 64), 256, 0, stream>>>(src, dst, K_, N_);
  };
  for (int l = 0; l < L; ++l) {
    size_t DD = (size_t)D * D, DF = (size_t)D * F;
    size_t oRD = (size_t)l * R * D, oRF = (size_t)l * R * F;
    T(wq + l * DD, wqkvT + (size_t)l * 3 * DD, D, D);
    T(wk + l * DD, wqkvT + (size_t)l * 3 * DD + DD, D, D);
    T(wv + l * DD, wqkvT + (size_t)l * 3 * DD + 2 * DD, D, D);
    T(wo + l * DD, woT + l * DD, D, D);
    T(wg + l * DF, wguT + (size_t)l * 2 * DF, D, F);
    T(wu + l * DF, wguT + (size_t)l * 2 * DF + DF, D, F);
    T(wd + l * DF, wdT + l * DF, F, D);
    { Ptr3 bp = {{bq + oRD, bk + oRD, bv + oRD}};
      build_bext_kernel<3><<<dim3(3 * D * 64 / 256), 256, 0, stream>>>(bp, beQKV + (size_t)l * 3 * D * 64, 10); }
    { Ptr3 bp = {{bo + oRD, nullptr, nullptr}};
      build_bext_kernel<1><<<dim3(D * 64 / 256), 256, 0, stream>>>(bp, beO + (size_t)l * D * 64, 10); }
    { Ptr3 bp = {{bg + oRF, bu + oRF, nullptr}};
      build_bext_kernel<2><<<dim3(2 * F * 64 / 256), 256, 0, stream>>>(bp, beGU + (size_t)l * 2 * F * 64, 12); }
    { Ptr3 bp = {{bd + oRD, nullptr, nullptr}};
      build_bext_kernel<1><<<dim3(D * 64 / 256), 256, 0, stream>>>(bp, beD + (size_t)l * D * 64, 10); }
  }
  T(lm_head_w, lmT, D, V);

  rope_cache_kernel<<<dim3(S), dim3(32), 0, stream>>>(cosb, sinb);
  embed_kernel<<<dim3(BS), dim3(256), 0, stream>>>(ids, emb, h);

  constexpr int ROPE_BLOCKS = (B * S * H * 32 + 255) / 256;

  for (int l = 0; l < L; ++l) {
    size_t DD = (size_t)D * D, DF = (size_t)D * F;
    size_t oDR = (size_t)l * D * R, oFR = (size_t)l * F * R;

    // ---- attention block ----
    { Ptr3 ap = {{aq + oDR, ak + oDR, av + oDR}};
      rms_lora_kernel<3><<<dim3(BS), 256, 0, stream>>>(h, ln1 + (size_t)l * D, ap, x_bf, t2e); }
    gemm_bf16_kernel<128, false, true><<<dim3(3 * D / 128, BS / 128), 256, 0, stream>>>(
        x_bf, wqkvT + (size_t)l * 3 * DD, qkv, BS, 3 * D, D, t2e, beQKV + (size_t)l * 3 * D * 64);
    rope_apply_qk_kernel<<<dim3(2 * ROPE_BLOCKS), 256, 0, stream>>>(qkv, cosb, sinb);

    attn_mfma_kernel<<<dim3(B * H * (S / 64)), 256, 0, stream>>>(qkv, amask, obf);

    lora_o_kernel<<<dim3(BS), 256, 0, stream>>>(obf, ao + oDR, t2e);
    gemm_bf16_kernel<64, true, true><<<dim3(D / 64, BS / 128), 256, 0, stream>>>(
        obf, woT + l * DD, h, BS, D, D, t2e, beO + (size_t)l * D * 64);

    // ---- MLP block ----
    { Ptr3 ap = {{ag + oDR, au + oDR, nullptr}};
      rms_lora_kernel<2><<<dim3(BS), 256, 0, stream>>>(h, ln2 + (size_t)l * D, ap, x_bf, t2e); }
    gemm_bf16_kernel<128, false, true><<<dim3(2 * F / 128, BS / 128), 256, 0, stream>>>(
        x_bf, wguT + (size_t)l * 2 * DF, gu, BS, 2 * F, D, t2e, beGU + (size_t)l * 2 * F * 64);

    silu_lora_kernel<<<dim3(BS), 256, 0, stream>>>(gu, ad + oFR, gbf, t2e);

    gemm_bf16_kernel<64, true, true><<<dim3(D / 64, BS / 128), 256, 0, stream>>>(
        gbf, wdT + l * DF, h, BS, D, F, t2e, beD + (size_t)l * D * 64);
  }

  // ---- final norm + heads ----
  rmsnorm_bf16_kernel<<<dim3(BS), 256, 0, stream>>>(h, final_ln, x_bf);
  gemm_bf16_kernel<128, false, false><<<dim3(V / 128, BS / 128), 256, 0, stream>>>(
      x_bf, lmT, logits, BS, V, D, nullptr, nullptr);
  value_kernel<<<dim3(BS), 256, 0, stream>>>(x_bf, value_w, value_b, values);
}

// Round 7
// 1022.237 us; speedup vs baseline: 1.3582x; 1.1125x over previous
//
#include <hip/hip_runtime.h>
#include <math.h>

// LLaMA-style decoder forward: B=2 S=512 D=1024 H=16 F=4096 V=32000 L=2 R=16
constexpr int B = 2, S = 512, D = 1024, H = 16, F = 4096, V = 32000, L = 2, R = 16, DH = 64;
constexpr int BS = B * S;          // 1024 rows
constexpr float LORA_SCALE = 2.0f; // alpha/r
constexpr float EPS = 1e-5f;
constexpr int RS_QKV = 3 * D;      // fused qkv row stride (ushorts)
constexpr int RS_GU  = 2 * F;      // fused g|u row stride (ushorts)

typedef __attribute__((ext_vector_type(8))) __bf16 bf16x8;
typedef __attribute__((ext_vector_type(4))) float f32x4;

__device__ __forceinline__ unsigned short f2bf(float f) {
  unsigned u = __builtin_bit_cast(unsigned, f);
  unsigned r = (u + 0x7FFFu + ((u >> 16) & 1u)) >> 16;  // RNE
  return (unsigned short)r;
}
__device__ __forceinline__ float bf2f(unsigned short us) {
  return __builtin_bit_cast(float, (unsigned)us << 16);
}
__device__ __forceinline__ void load_lds16(const void* g, void* l) {
  __builtin_amdgcn_global_load_lds((const __attribute__((address_space(1))) void*)g,
                                   (__attribute__((address_space(3))) void*)l, 16, 0, 0);
}

struct Ptr3 { const float* p[3]; };

// ---------------- RoPE cache ----------------
__global__ void rope_cache_kernel(float* __restrict__ cosb, float* __restrict__ sinb) {
  int s = blockIdx.x, j = threadIdx.x;  // j in [0,32)
  float inv = __expf(-(float)j * (9.210340371976184f / 32.0f));
  float ang = (float)s * inv;
  float c = cosf(ang), sn = sinf(ang);
  cosb[s * DH + j] = c;  cosb[s * DH + j + 32] = c;
  sinb[s * DH + j] = sn; sinb[s * DH + j + 32] = sn;
}

// ---------------- Embedding gather ----------------
__global__ void embed_kernel(const int* __restrict__ ids, const float* __restrict__ emb,
                             float* __restrict__ h) {
  int row = blockIdx.x, t = threadIdx.x;
  int id = ids[row];
  ((float4*)(h + (size_t)row * D))[t] = ((const float4*)(emb + (size_t)id * D))[t];
}

// ---------------- RMSNorm -> bf16 (final norm) ----------------
__global__ void rmsnorm_bf16_kernel(const float* __restrict__ x, const float* __restrict__ w,
                                    unsigned short* __restrict__ y) {
  int row = blockIdx.x, t = threadIdx.x;
  float4 xv = ((const float4*)(x + (size_t)row * D))[t];
  float ss = xv.x * xv.x + xv.y * xv.y + xv.z * xv.z + xv.w * xv.w;
  __shared__ float red[256];
  red[t] = ss; __syncthreads();
  for (int s2 = 128; s2; s2 >>= 1) { if (t < s2) red[t] += red[t + s2]; __syncthreads(); }
  float rinv = rsqrtf(red[0] * (1.0f / D) + EPS);
  float4 wv = ((const float4*)w)[t];
  ushort4 o;
  o.x = f2bf(xv.x * rinv * wv.x); o.y = f2bf(xv.y * rinv * wv.y);
  o.z = f2bf(xv.z * rinv * wv.z); o.w = f2bf(xv.w * rinv * wv.w);
  ((ushort4*)(y + (size_t)row * D))[t] = o;
}

// ---------------- Fused RMSNorm + LoRA down-proj ----------------
template <int NA>
__global__ void rms_lora_kernel(const float* __restrict__ hp, const float* __restrict__ w,
                                Ptr3 ap, unsigned short* __restrict__ xbf,
                                unsigned short* __restrict__ t2e) {
  int row = blockIdx.x, t = threadIdx.x;  // 256 threads
  __shared__ float xs[D];
  __shared__ float red[256];
  float4 xv = ((const float4*)(hp + (size_t)row * D))[t];
  float ss = xv.x * xv.x + xv.y * xv.y + xv.z * xv.z + xv.w * xv.w;
  red[t] = ss; __syncthreads();
  for (int s2 = 128; s2; s2 >>= 1) { if (t < s2) red[t] += red[t + s2]; __syncthreads(); }
  float rinv = rsqrtf(red[0] * (1.0f / D) + EPS);
  float4 wv = ((const float4*)w)[t];
  float4 nx;
  nx.x = xv.x * rinv * wv.x; nx.y = xv.y * rinv * wv.y;
  nx.z = xv.z * rinv * wv.z; nx.w = xv.w * rinv * wv.w;
  xs[t * 4 + 0] = nx.x; xs[t * 4 + 1] = nx.y; xs[t * 4 + 2] = nx.z; xs[t * 4 + 3] = nx.w;
  ushort4 o;
  o.x = f2bf(nx.x); o.y = f2bf(nx.y); o.z = f2bf(nx.z); o.w = f2bf(nx.w);
  ((ushort4*)(xbf + (size_t)row * D))[t] = o;
  if (t >= NA * 16 && t < 64) t2e[(size_t)row * 64 + t] = 0;
  __syncthreads();
  int n = t & 15, g = t >> 4;
#pragma unroll
  for (int ad = 0; ad < NA; ++ad) {
    const float* a = ap.p[ad];
    float s = 0.0f;
    for (int k = g; k < D; k += 16) s = fmaf(xs[k], a[k * 16 + n], s);
    red[t] = s; __syncthreads();
    for (int h2 = 128; h2 >= 16; h2 >>= 1) { if (t < h2) red[t] += red[t + h2]; __syncthreads(); }
    if (t < 16) t2e[(size_t)row * 64 + ad * 16 + t] = f2bf(LORA_SCALE * red[t]);
    __syncthreads();
  }
}

// ---------------- LoRA down-proj from bf16 activation (o-proj) ----------------
__global__ void lora_o_kernel(const unsigned short* __restrict__ xb, const float* __restrict__ a,
                              unsigned short* __restrict__ t2e) {
  int row = blockIdx.x, t = threadIdx.x;  // 256 threads, K=D
  __shared__ float xs[D];
  __shared__ float red[256];
  for (int k = t; k < D; k += 256) xs[k] = bf2f(xb[(size_t)row * D + k]);
  if (t >= 16 && t < 64) t2e[(size_t)row * 64 + t] = 0;
  __syncthreads();
  int n = t & 15, g = t >> 4;
  float s = 0.0f;
  for (int k = g; k < D; k += 16) s = fmaf(xs[k], a[k * 16 + n], s);
  red[t] = s; __syncthreads();
  for (int h2 = 128; h2 >= 16; h2 >>= 1) { if (t < h2) red[t] += red[t + h2]; __syncthreads(); }
  if (t < 16) t2e[(size_t)row * 64 + t] = f2bf(LORA_SCALE * red[t]);
}

// ---------------- Fused SwiGLU (bf16 in) + LoRA down-proj ----------------
__global__ void silu_lora_kernel(const unsigned short* __restrict__ gub, const float* __restrict__ a,
                                 unsigned short* __restrict__ gbf, unsigned short* __restrict__ t2e) {
  int row = blockIdx.x, t = threadIdx.x;  // 256 threads
  __shared__ float xs[F];   // 16KB
  __shared__ float red[256];
#pragma unroll
  for (int i2 = 0; i2 < 2; ++i2) {
    int idx = i2 * 256 + t;   // 512 chunks of 8 bf16
    uint4 gv = ((const uint4*)(gub + (size_t)row * RS_GU))[idx];
    uint4 uv = ((const uint4*)(gub + (size_t)row * RS_GU + F))[idx];
    const unsigned* gw = (const unsigned*)&gv;
    const unsigned* uw = (const unsigned*)&uv;
    unsigned short go[8];
#pragma unroll
    for (int q = 0; q < 4; ++q) {
      float g0 = bf2f((unsigned short)(gw[q] & 0xffff)), g1 = bf2f((unsigned short)(gw[q] >> 16));
      float u0 = bf2f((unsigned short)(uw[q] & 0xffff)), u1 = bf2f((unsigned short)(uw[q] >> 16));
      float r0 = g0 / (1.0f + __expf(-g0)) * u0;
      float r1 = g1 / (1.0f + __expf(-g1)) * u1;
      xs[idx * 8 + q * 2] = r0; xs[idx * 8 + q * 2 + 1] = r1;
      go[q * 2] = f2bf(r0); go[q * 2 + 1] = f2bf(r1);
    }
    *(uint4*)(gbf + (size_t)row * F + idx * 8) = *(const uint4*)go;
  }
  if (t >= 16 && t < 64) t2e[(size_t)row * 64 + t] = 0;
  __syncthreads();
  int n = t & 15, g = t >> 4;
  float s = 0.0f;
  for (int k = g; k < F; k += 16) s = fmaf(xs[k], a[k * 16 + n], s);
  red[t] = s; __syncthreads();
  for (int h2 = 128; h2 >= 16; h2 >>= 1) { if (t < h2) red[t] += red[t + h2]; __syncthreads(); }
  if (t < 16) t2e[(size_t)row * 64 + t] = f2bf(LORA_SCALE * red[t]);
}

// ---------------- Merged bext builder (all layers, one dispatch) ----------------
struct BD { const float* p0; const float* p1; const float* p2;
            unsigned short* dst; int NA; int logW; int nelem; };
struct BDs { BD d[8]; };
__global__ void bext_many_kernel(BDs da) {
  int gid = blockIdx.x * 256 + threadIdx.x;
  int di = 0;
  while (gid >= da.d[di].nelem) { gid -= da.d[di].nelem; ++di; }  // nelem % 256 == 0: uniform
  const BD dd = da.d[di];
  int n = gid >> 6, kk = gid & 63;
  int W = 1 << dd.logW;
  int sel = n >> dd.logW;
  const float* bp = (sel == 0) ? dd.p0 : (sel == 1) ? dd.p1 : dd.p2;
  float v = 0.0f;
  if ((kk >> 4) == sel && sel < dd.NA)
    v = bp[(size_t)(kk & 15) * W + (n & (W - 1))];
  dd.dst[(size_t)n * 64 + kk] = f2bf(v);
}

// ---------------- Merged f32 [K,N] -> bf16 [N,K] transposes (one dispatch) ----------------
struct TD { const float* src; unsigned short* dst; int K; int N; int nblk; };
struct TDs { TD d[15]; };
__global__ __launch_bounds__(256) void transpose_many_kernel(TDs da) {
  __shared__ unsigned short tile[64 * 68];
  int bid = blockIdx.x;
  int di = 0;
  while (bid >= da.d[di].nblk) { bid -= da.d[di].nblk; ++di; }
  const TD dd = da.d[di];
  int nbx = dd.N >> 6;
  int n0 = (bid % nbx) * 64, k0 = (bid / nbx) * 64;
  int t = threadIdx.x;
  int rr = t >> 4, c4 = (t & 15) << 2;
#pragma unroll
  for (int i = 0; i < 4; ++i) {
    int row = i * 16 + rr;
    float4 v = *(const float4*)(dd.src + (size_t)(k0 + row) * dd.N + n0 + c4);
    tile[(c4 + 0) * 68 + row] = f2bf(v.x);
    tile[(c4 + 1) * 68 + row] = f2bf(v.y);
    tile[(c4 + 2) * 68 + row] = f2bf(v.z);
    tile[(c4 + 3) * 68 + row] = f2bf(v.w);
  }
  __syncthreads();
#pragma unroll
  for (int i = 0; i < 4; ++i) {
    int row = i * 16 + rr;
    *(ushort4*)(dd.dst + (size_t)(n0 + row) * dd.K + k0 + c4) = *(const ushort4*)(tile + row * 68 + c4);
  }
}

// ---------------- bf16 MFMA GEMM: depth-2 pipeline + T2 XOR swizzle + LoRA K-ext ----------------
// C = [C +] A @ Bt^T [+ Ae @ Be^T].
// T2 (rule #21 both-sides): LDS dest linear (global_load_lds requirement); global SOURCE chunk
// pre-permuted c8^(row&7); ds_read applies the same XOR -> 16-way read conflict becomes 2-way.
// OM: 0 = f32 out (opt ACC), 1 = bf16 out, 2 = bf16 out + RoPE on cols < 2*D (qkv).
template <int BN, bool ACC, bool EXT, int OM>
__global__ __launch_bounds__(256) void gemm_bf16_kernel(
    const unsigned short* __restrict__ A, const unsigned short* __restrict__ Bt,
    void* __restrict__ Cp, int M, int N, int K,
    const unsigned short* __restrict__ Ae, const unsigned short* __restrict__ Be,
    const float* __restrict__ cosb, const float* __restrict__ sinb) {
  constexpr int WM = (BN == 128) ? 2 : 4;
  constexpr int RW = 128 / WM;
  constexpr int MI = RW / 16;
  constexpr int BCH = BN / 32;
  __shared__ __align__(16) unsigned short As[2][128 * 64];
  __shared__ __align__(16) unsigned short Bs[2][BN * 64];
  int t = threadIdx.x;
  int lane = t & 63, wave = t >> 6;
  int wr = (BN == 128) ? (wave >> 1) : wave;
  int wc = (BN == 128) ? (wave & 1) : 0;
  int MT = gridDim.y, NT = gridDim.x;
  int nwg = MT * NT;
  int orig = blockIdx.y * NT + blockIdx.x;
  int qq = nwg >> 3, rr8 = nwg & 7;
  int xcd = orig & 7, pos = orig >> 3;
  int wg = (xcd < rr8) ? (xcd * (qq + 1) + pos) : (rr8 * (qq + 1) + (xcd - rr8) * qq + pos);
  int m0 = (wg % MT) * 128, n0 = (wg / MT) * BN;
  int fr = lane & 15, fq = lane >> 4;
  int xorv = fr & 7;                       // row&7 for all fragment rows (bases are %8==0)
  f32x4 acc[MI][4] = {};
  int kIters = K / 64;
  int nIters = EXT ? kIters + 1 : kIters;

  auto STAGE = [&](int it, int buf) {
    bool ext = EXT && (it == kIters);
    int k0 = it * 64;
#pragma unroll
    for (int c = 0; c < 4; ++c) {
      int i = c * 256 + t;
      int row = i >> 3, c8 = i & 7;
      int sc = (c8 ^ (row & 7)) * 8;       // inverse-swizzled global source chunk
      const unsigned short* src = ext ? (Ae + (size_t)(m0 + row) * 64 + sc)
                                      : (A + (size_t)(m0 + row) * K + k0 + sc);
      load_lds16(src, &As[buf][i * 8]);
    }
#pragma unroll
    for (int c = 0; c < BCH; ++c) {
      int i = c * 256 + t;
      int row = i >> 3, c8 = i & 7;
      int sc = (c8 ^ (row & 7)) * 8;
      const unsigned short* src = ext ? (Be + (size_t)(n0 + row) * 64 + sc)
                                      : (Bt + (size_t)(n0 + row) * K + k0 + sc);
      load_lds16(src, &Bs[buf][i * 8]);
    }
  };

  STAGE(0, 0);
  if (nIters > 1) STAGE(1, 1);
  int cur = 0;
  for (int it = 0; it < nIters; ++it) {
    if (it + 1 < nIters) {
      if constexpr (BN == 128) asm volatile("s_waitcnt vmcnt(8)" ::: "memory");
      else                     asm volatile("s_waitcnt vmcnt(6)" ::: "memory");
    } else {
      asm volatile("s_waitcnt vmcnt(0)" ::: "memory");
    }
    __builtin_amdgcn_s_barrier();
#pragma unroll
    for (int kk = 0; kk < 2; ++kk) {
      bf16x8 af[MI], bfr[4];
#pragma unroll
      for (int mi = 0; mi < MI; ++mi)
        af[mi] = *(const bf16x8*)(&As[cur][(wr * RW + mi * 16 + fr) * 64 + (((kk * 4 + fq) ^ xorv) << 3)]);
#pragma unroll
      for (int ni = 0; ni < 4; ++ni)
        bfr[ni] = *(const bf16x8*)(&Bs[cur][(wc * 64 + ni * 16 + fr) * 64 + (((kk * 4 + fq) ^ xorv) << 3)]);
#pragma unroll
      for (int mi = 0; mi < MI; ++mi)
#pragma unroll
        for (int ni = 0; ni < 4; ++ni)
          acc[mi][ni] = __builtin_amdgcn_mfma_f32_16x16x32_bf16(af[mi], bfr[ni], acc[mi][ni], 0, 0, 0);
    }
    __builtin_amdgcn_s_barrier();
    if (it + 2 < nIters) STAGE(it + 2, cur);
    cur ^= 1;
  }
  // epilogue (C/D layout: col=lane&15, row=(lane>>4)*4+j)
  if constexpr (OM == 0) {
    float* C = (float*)Cp;
#pragma unroll
    for (int mi = 0; mi < MI; ++mi)
#pragma unroll
      for (int ni = 0; ni < 4; ++ni)
#pragma unroll
        for (int j = 0; j < 4; ++j) {
          int r = m0 + wr * RW + mi * 16 + fq * 4 + j;
          int cl = n0 + wc * 64 + ni * 16 + fr;
          size_t idx = (size_t)r * N + cl;
          float v = acc[mi][ni][j];
          C[idx] = ACC ? C[idx] + v : v;
        }
  } else {
    unsigned short* Cb = (unsigned short*)Cp;
#pragma unroll
    for (int mi = 0; mi < MI; ++mi)
#pragma unroll
      for (int j = 0; j < 4; ++j) {
        int r = m0 + wr * RW + mi * 16 + fq * 4 + j;
        if constexpr (OM == 2) {
          int s = r & (S - 1);
#pragma unroll
          for (int ni = 0; ni < 2; ++ni) {
            int cl0 = n0 + wc * 64 + ni * 16 + fr;   // dh = cl0&63 < 32
            int cl1 = cl0 + 32;
            float x0 = acc[mi][ni][j], x1 = acc[mi][ni + 2][j];
            if (cl0 < 2 * D) {                       // q or k head -> rope
              int dh = cl0 & 63;
              float cz = cosb[s * DH + dh], sz = sinb[s * DH + dh];
              float y0 = x0 * cz - x1 * sz;
              float y1 = x1 * cz + x0 * sz;
              x0 = y0; x1 = y1;
            }
            Cb[(size_t)r * N + cl0] = f2bf(x0);
            Cb[(size_t)r * N + cl1] = f2bf(x1);
          }
        } else {
#pragma unroll
          for (int ni = 0; ni < 4; ++ni) {
            int cl = n0 + wc * 64 + ni * 16 + fr;
            Cb[(size_t)r * N + cl] = f2bf(acc[mi][ni][j]);
          }
        }
      }
  }
}

// ---------------- Flash attention, bf16 MFMA (bf16 qkv input) ----------------
__global__ __launch_bounds__(256) void attn_mfma_kernel(
    const unsigned short* __restrict__ qkvb, const int* __restrict__ amask,
    unsigned short* __restrict__ o) {
  __shared__ unsigned short Qs[64 * 72];
  __shared__ unsigned short Ks[64 * 72];
  __shared__ unsigned short Vt[64 * 72];   // [dh][key]
  __shared__ unsigned short Ps[4][16 * 72];
  __shared__ float msk[64];
  int bid = blockIdx.x;
  int qt = bid & 7, hh = (bid >> 3) & (H - 1), b = bid >> 7;
  int t = threadIdx.x;
  int lane = t & 63, w = t >> 6;
  int fr = lane & 15, fq = lane >> 4;
  size_t rowbase = (size_t)b * S;
  int q0 = qt * 64;
  const float scale = 0.125f;  // 1/sqrt(64)
#pragma unroll
  for (int c = 0; c < 2; ++c) {
    int i = c * 256 + t;
    int row = i >> 3, ch = i & 7;
    uint4 v = *(const uint4*)(qkvb + (rowbase + q0 + row) * RS_QKV + hh * DH + ch * 8);
    *(uint4*)(Qs + row * 72 + ch * 8) = v;
  }
  f32x4 oacc[4] = {};
  float m_old[4] = {-1e30f, -1e30f, -1e30f, -1e30f};
  float l[4] = {};
  int qbase = q0 + w * 16;
  for (int kt = 0; kt <= qt; ++kt) {
    int kk0 = kt * 64;
#pragma unroll
    for (int c = 0; c < 2; ++c) {
      int i = c * 256 + t;
      int row = i >> 3, ch = i & 7;
      uint4 kv = *(const uint4*)(qkvb + (rowbase + kk0 + row) * RS_QKV + D + hh * DH + ch * 8);
      *(uint4*)(Ks + row * 72 + ch * 8) = kv;
      uint4 vv = *(const uint4*)(qkvb + (rowbase + kk0 + row) * RS_QKV + 2 * D + hh * DH + ch * 8);
      const unsigned short* vs = (const unsigned short*)&vv;
#pragma unroll
      for (int q = 0; q < 8; ++q) Vt[(ch * 8 + q) * 72 + row] = vs[q];
    }
    if (t < 64) msk[t] = (amask[b * S + kk0 + t] > 0) ? 0.0f : -1e9f;
    __syncthreads();
    bf16x8 aq[2];
    aq[0] = *(const bf16x8*)(Qs + (w * 16 + fr) * 72 + fq * 8);
    aq[1] = *(const bf16x8*)(Qs + (w * 16 + fr) * 72 + 32 + fq * 8);
    f32x4 sacc[4];
#pragma unroll
    for (int ct = 0; ct < 4; ++ct) {
      bf16x8 bk0 = *(const bf16x8*)(Ks + (ct * 16 + fr) * 72 + fq * 8);
      bf16x8 bk1 = *(const bf16x8*)(Ks + (ct * 16 + fr) * 72 + 32 + fq * 8);
      f32x4 z = {};
      z = __builtin_amdgcn_mfma_f32_16x16x32_bf16(aq[0], bk0, z, 0, 0, 0);
      sacc[ct] = __builtin_amdgcn_mfma_f32_16x16x32_bf16(aq[1], bk1, z, 0, 0, 0);
    }
    float sv[4][4];
#pragma unroll
    for (int ct = 0; ct < 4; ++ct) {
      int kg = kk0 + ct * 16 + fr;
      float mk = msk[ct * 16 + fr];
#pragma unroll
      for (int j = 0; j < 4; ++j) {
        int qg = qbase + fq * 4 + j;
        float s = sacc[ct][j] * scale + mk;
        sv[ct][j] = (kg > qg) ? -1e9f : s;
      }
    }
    float mnew[4], f[4], rsum[4];
#pragma unroll
    for (int j = 0; j < 4; ++j) {
      float mt = fmaxf(fmaxf(sv[0][j], sv[1][j]), fmaxf(sv[2][j], sv[3][j]));
      for (int off = 1; off < 16; off <<= 1) mt = fmaxf(mt, __shfl_xor(mt, off));
      mnew[j] = fmaxf(m_old[j], mt);
      f[j] = __expf(m_old[j] - mnew[j]);
      float rs = 0.0f;
#pragma unroll
      for (int ct = 0; ct < 4; ++ct) {
        float e = __expf(sv[ct][j] - mnew[j]);
        sv[ct][j] = e;
        rs += e;
      }
      for (int off = 1; off < 16; off <<= 1) rs += __shfl_xor(rs, off);
      rsum[j] = rs;
      l[j] = l[j] * f[j] + rsum[j];
      m_old[j] = mnew[j];
#pragma unroll
      for (int dt = 0; dt < 4; ++dt) oacc[dt][j] *= f[j];
    }
#pragma unroll
    for (int ct = 0; ct < 4; ++ct)
#pragma unroll
      for (int j = 0; j < 4; ++j)
        Ps[w][(fq * 4 + j) * 72 + ct * 16 + fr] = f2bf(sv[ct][j]);
    __syncthreads();
    bf16x8 pa[2];
    pa[0] = *(const bf16x8*)(&Ps[w][fr * 72 + fq * 8]);
    pa[1] = *(const bf16x8*)(&Ps[w][fr * 72 + 32 + fq * 8]);
#pragma unroll
    for (int dt = 0; dt < 4; ++dt) {
      bf16x8 vb0 = *(const bf16x8*)(Vt + (dt * 16 + fr) * 72 + fq * 8);
      bf16x8 vb1 = *(const bf16x8*)(Vt + (dt * 16 + fr) * 72 + 32 + fq * 8);
      oacc[dt] = __builtin_amdgcn_mfma_f32_16x16x32_bf16(pa[0], vb0, oacc[dt], 0, 0, 0);
      oacc[dt] = __builtin_amdgcn_mfma_f32_16x16x32_bf16(pa[1], vb1, oacc[dt], 0, 0, 0);
    }
    __syncthreads();
  }
#pragma unroll
  for (int j = 0; j < 4; ++j) {
    float rinv = 1.0f / l[j];
    int qrow = qbase + fq * 4 + j;
#pragma unroll
    for (int dt = 0; dt < 4; ++dt)
      o[(rowbase + qrow) * D + hh * DH + dt * 16 + fr] = f2bf(oacc[dt][j] * rinv);
  }
}

// ---------------- Value head ----------------
__global__ void value_kernel(const unsigned short* __restrict__ hf, const float* __restrict__ vw,
                             const float* __restrict__ vb, float* __restrict__ out) {
  int row = blockIdx.x, t = threadIdx.x;
  float acc = 0.0f;
  for (int d = t; d < D; d += 256) acc = fmaf(bf2f(hf[(size_t)row * D + d]), vw[d], acc);
  __shared__ float red[256];
  red[t] = acc; __syncthreads();
  for (int s2 = 128; s2; s2 >>= 1) { if (t < s2) red[t] += red[t + s2]; __syncthreads(); }
  if (t == 0) out[row] = red[0] + vb[0];
}

extern "C" void kernel_launch(void* const* d_in, const int* in_sizes, int n_in,
                              void* d_out, int out_size, void* d_ws, size_t ws_size,
                              hipStream_t stream) {
  const int*   ids     = (const int*)d_in[0];
  const int*   amask   = (const int*)d_in[1];
  const float* emb     = (const float*)d_in[2];
  const float* ln1     = (const float*)d_in[3];
  const float* ln2     = (const float*)d_in[4];
  const float* wq = (const float*)d_in[5],  *aq = (const float*)d_in[6],  *bq = (const float*)d_in[7];
  const float* wk = (const float*)d_in[8],  *ak = (const float*)d_in[9],  *bk = (const float*)d_in[10];
  const float* wv = (const float*)d_in[11], *av = (const float*)d_in[12], *bv = (const float*)d_in[13];
  const float* wo = (const float*)d_in[14], *ao = (const float*)d_in[15], *bo = (const float*)d_in[16];
  const float* wg = (const float*)d_in[17], *ag = (const float*)d_in[18], *bg = (const float*)d_in[19];
  const float* wu = (const float*)d_in[20], *au = (const float*)d_in[21], *bu = (const float*)d_in[22];
  const float* wd = (const float*)d_in[23], *ad = (const float*)d_in[24], *bd = (const float*)d_in[25];
  const float* final_ln  = (const float*)d_in[26];
  const float* lm_head_w = (const float*)d_in[27];
  const float* value_w   = (const float*)d_in[28];
  const float* value_b   = (const float*)d_in[29];

  float* out    = (float*)d_out;
  float* logits = out;
  float* values = out + (size_t)BS * V;

  // ---- workspace ----
  float* Wf = (float*)d_ws;
  float* cosb = Wf; Wf += S * DH;
  float* sinb = Wf; Wf += S * DH;
  float* h    = Wf; Wf += (size_t)BS * D;
  unsigned short* Wb = (unsigned short*)Wf;
  unsigned short* x_bf  = Wb; Wb += (size_t)BS * D;
  unsigned short* t2e   = Wb; Wb += (size_t)BS * 64;
  unsigned short* qg    = Wb; Wb += (size_t)BS * F;      // shared: qkv_bf (3D) / gbf (F)
  unsigned short* gu_bf = Wb; Wb += (size_t)BS * RS_GU;  // obf aliases its head
  unsigned short* wqkvT = Wb; Wb += (size_t)L * 3 * D * D;
  unsigned short* woT   = Wb; Wb += (size_t)L * D * D;
  unsigned short* wguT  = Wb; Wb += (size_t)L * 2 * D * F;
  unsigned short* wdT   = Wb; Wb += (size_t)L * F * D;
  unsigned short* lmT   = Wb; Wb += (size_t)D * V;
  unsigned short* beQKV = Wb; Wb += (size_t)L * 3 * D * 64;
  unsigned short* beO   = Wb; Wb += (size_t)L * D * 64;
  unsigned short* beGU  = Wb; Wb += (size_t)L * 2 * F * 64;
  unsigned short* beD   = Wb; Wb += (size_t)L * D * 64;
  unsigned short* qkv_bf = qg;                 // [BS][3D]
  unsigned short* gbf    = qg;                 // [BS][F]
  unsigned short* obf    = gu_bf;              // [BS][D]

  // ---- merged weight transposes (15 -> 1 dispatch) ----
  TDs td; int tblocks = 0; int di = 0;
  auto addT = [&](const float* s, unsigned short* dp, int K_, int N_) {
    td.d[di] = {s, dp, K_, N_, (K_ / 64) * (N_ / 64)};
    tblocks += td.d[di].nblk; ++di;
  };
  for (int l = 0; l < L; ++l) {
    size_t DD = (size_t)D * D, DF = (size_t)D * F;
    addT(wq + l * DD, wqkvT + (size_t)l * 3 * DD, D, D);
    addT(wk + l * DD, wqkvT + (size_t)l * 3 * DD + DD, D, D);
    addT(wv + l * DD, wqkvT + (size_t)l * 3 * DD + 2 * DD, D, D);
    addT(wo + l * DD, woT + l * DD, D, D);
    addT(wg + l * DF, wguT + (size_t)l * 2 * DF, D, F);
    addT(wu + l * DF, wguT + (size_t)l * 2 * DF + DF, D, F);
    addT(wd + l * DF, wdT + l * DF, F, D);
  }
  addT(lm_head_w, lmT, D, V);
  transpose_many_kernel<<<dim3(tblocks), 256, 0, stream>>>(td);

  // ---- merged bext (8 -> 1 dispatch) ----
  BDs bd2; int belems = 0; di = 0;
  auto addB = [&](const float* p0, const float* p1, const float* p2,
                  unsigned short* dst, int NA, int logW, int N_) {
    bd2.d[di] = {p0, p1, p2, dst, NA, logW, N_ * 64};
    belems += N_ * 64; ++di;
  };
  for (int l = 0; l < L; ++l) {
    size_t oRD = (size_t)l * R * D, oRF = (size_t)l * R * F;
    addB(bq + oRD, bk + oRD, bv + oRD, beQKV + (size_t)l * 3 * D * 64, 3, 10, 3 * D);
    addB(bo + oRD, nullptr, nullptr,   beO   + (size_t)l * D * 64,     1, 10, D);
    addB(bg + oRF, bu + oRF, nullptr,  beGU  + (size_t)l * 2 * F * 64, 2, 12, 2 * F);
    addB(bd + oRD, nullptr, nullptr,   beD   + (size_t)l * D * 64,     1, 10, D);
  }
  bext_many_kernel<<<dim3(belems / 256), 256, 0, stream>>>(bd2);

  rope_cache_kernel<<<dim3(S), dim3(32), 0, stream>>>(cosb, sinb);
  embed_kernel<<<dim3(BS), dim3(256), 0, stream>>>(ids, emb, h);

  for (int l = 0; l < L; ++l) {
    size_t DD = (size_t)D * D, DF = (size_t)D * F;
    size_t oDR = (size_t)l * D * R, oFR = (size_t)l * F * R;

    // ---- attention block ----
    { Ptr3 ap = {{aq + oDR, ak + oDR, av + oDR}};
      rms_lora_kernel<3><<<dim3(BS), 256, 0, stream>>>(h, ln1 + (size_t)l * D, ap, x_bf, t2e); }
    gemm_bf16_kernel<128, false, true, 2><<<dim3(3 * D / 128, BS / 128), 256, 0, stream>>>(
        x_bf, wqkvT + (size_t)l * 3 * DD, qkv_bf, BS, 3 * D, D,
        t2e, beQKV + (size_t)l * 3 * D * 64, cosb, sinb);

    attn_mfma_kernel<<<dim3(B * H * (S / 64)), 256, 0, stream>>>(qkv_bf, amask, obf);

    lora_o_kernel<<<dim3(BS), 256, 0, stream>>>(obf, ao + oDR, t2e);
    gemm_bf16_kernel<64, true, true, 0><<<dim3(D / 64, BS / 128), 256, 0, stream>>>(
        obf, woT + l * DD, h, BS, D, D, t2e, beO + (size_t)l * D * 64, nullptr, nullptr);

    // ---- MLP block ----
    { Ptr3 ap = {{ag + oDR, au + oDR, nullptr}};
      rms_lora_kernel<2><<<dim3(BS), 256, 0, stream>>>(h, ln2 + (size_t)l * D, ap, x_bf, t2e); }
    gemm_bf16_kernel<128, false, true, 1><<<dim3(2 * F / 128, BS / 128), 256, 0, stream>>>(
        x_bf, wguT + (size_t)l * 2 * DF, gu_bf, BS, 2 * F, D,
        t2e, beGU + (size_t)l * 2 * F * 64, nullptr, nullptr);

    silu_lora_kernel<<<dim3(BS), 256, 0, stream>>>(gu_bf, ad + oFR, gbf, t2e);

    gemm_bf16_kernel<64, true, true, 0><<<dim3(D / 64, BS / 128), 256, 0, stream>>>(
        gbf, wdT + l * DF, h, BS, D, F, t2e, beD + (size_t)l * D * 64, nullptr, nullptr);
  }

  // ---- final norm + heads ----
  rmsnorm_bf16_kernel<<<dim3(BS), 256, 0, stream>>>(h, final_ln, x_bf);
  gemm_bf16_kernel<128, false, false, 0><<<dim3(V / 128, BS / 128), 256, 0, stream>>>(
      x_bf, lmT, logits, BS, V, D, nullptr, nullptr, nullptr, nullptr);
  value_kernel<<<dim3(BS), 256, 0, stream>>>(x_bf, value_w, value_b, values);
}